// Round 3
// baseline (1355.504 us; speedup 1.0000x reference)
//
#include <hip/hip_runtime.h>
#include <hip/hip_bf16.h>

// Problem constants (B=8, N=4096, M=N/4, K=64, C_in=64, h=128)
#define BB   8
#define NN   4096
#define MM   1024
#define KK   64
#define CIN  64
#define HH   128

// f32 radius^2 predicate: largest f32 <= 0.2*0.2 (f64) = 0x3D23D70A.
#define R2F 0.039999999105930328f

// Inputs: f32, dict order. Output: f32, values bf16-rounded (matches np ref).
static __device__ __forceinline__ float rnd_bf16(float v) {
    return __bfloat162float(__float2bfloat16(v));
}
// Manual RNE f32->bf16 (finite inputs only; matches RNE for our h2 values).
static __device__ __forceinline__ unsigned int bf16bits(float v) {
    unsigned int u = __float_as_uint(v);
    return (u + 0x7FFFu + ((u >> 16) & 1u)) >> 16;
}

// Wave64 max-reduce of a (hi,lo) u64 key via DPP (in-VALU lane moves, ~2cy
// issue each -- NOT ds_permute, which R15 proved slow). Standard rocPRIM
// sequence: row_shr 1,2,4,8 then row_bcast15, row_bcast31 -> lane 63 holds
// the wave max. bound_ctrl=1 zero-fills invalid lanes; key>0 always, so a
// zero partner never wins. Max over distinct keys == old 256-lane atomic.
static __device__ __forceinline__ void wave_max_key(unsigned int& hi,
                                                    unsigned int& lo) {
#define DPP_STEP(ctrl)                                                        \
    {                                                                         \
        unsigned int h2 = (unsigned int)__builtin_amdgcn_update_dpp(          \
            0, (int)hi, (ctrl), 0xF, 0xF, true);                              \
        unsigned int l2 = (unsigned int)__builtin_amdgcn_update_dpp(          \
            0, (int)lo, (ctrl), 0xF, 0xF, true);                              \
        if (h2 > hi || (h2 == hi && l2 > lo)) { hi = h2; lo = l2; }           \
    }
    DPP_STEP(0x111)  // row_shr:1
    DPP_STEP(0x112)  // row_shr:2
    DPP_STEP(0x114)  // row_shr:4
    DPP_STEP(0x118)  // row_shr:8
    DPP_STEP(0x142)  // row_bcast:15
    DPP_STEP(0x143)  // row_bcast:31
#undef DPP_STEP
}

// ---------------------------------------------------------------------------
// Kernel 1 (merged): FPS (blocks 0..7) + featmlp (blocks 8..135) + pw3T
// transpose (block 136) running concurrently on otherwise-idle CUs.
// FPS ledger: R11 base=631us. R12 512thr=790. R13 4-slot+f4=694. R15
// shfl-butterfly(ds_permute)=1068. R16 pk-asm+tree+4x64atomic=772 (atomics
// to 4 addrs serialize same as 1; SQ_LDS_BANK_CONFLICT identical). R18
// (this): keep R11 body but replace the 256-lane same-addr atomicMax
// (~260cy) with DPP wave-reduce (+1 atomic per wave, 4 total). Marker:
// SQ_LDS_BANK_CONFLICT must drop ~60x; if unchanged, DPP didn't displace
// the atomic cost -- revert.
// Key = (bits(d)<<32) | ~idx: u64 max == largest d, ties -> smallest idx
// (= np.argmax first-occurrence; d >= 0 so IEEE bits monotone).
// ---------------------------------------------------------------------------
__global__ __launch_bounds__(256) void fps_featmlp_kernel(
    const float* __restrict__ pts,            // [B,3,N] f32
    float* __restrict__ centf,                // ws [B,M,3] f32 (exact)
    float* __restrict__ outc,                 // d_out (first B*M*3), f32
    const float* __restrict__ feat,           // [B,CIN,N] f32
    const float* __restrict__ fw1, const float* __restrict__ fb1,
    const float* __restrict__ fw2, const float* __restrict__ fb2,
    const float* __restrict__ fw3, const float* __restrict__ fb3,
    __hip_bfloat16* __restrict__ fout,        // ws [B,N,HH] bf16
    const float* __restrict__ pw3,            // [HH,CIN] f32
    float* __restrict__ pw3T)                 // ws [CIN,HH] f32
{
    __shared__ float smem[3 * NN];            // fps: lx/ly/lz; featmlp: w1/w2
    __shared__ unsigned long long akey[4];
    const int t = threadIdx.x;

    if (blockIdx.x < BB) {
        // ================= FPS path (R11 body + DPP reduce) =================
        const int b = blockIdx.x;
        float* lx = smem;
        float* ly = smem + NN;
        float* lz = smem + 2 * NN;

        const float* px = pts + (size_t)b * 3 * NN;
        float x[16], y[16], z[16], mind[16];
#pragma unroll
        for (int i = 0; i < 16; ++i) {
            int p = t + i * 256;              // coalesced
            x[i] = px[p];
            y[i] = px[NN + p];
            z[i] = px[2 * NN + p];
            lx[p] = x[i]; ly[p] = y[i]; lz[p] = z[i];
            mind[i] = 3.4e38f;
        }
        if (t < 4) akey[t] = 0ULL;
        __syncthreads();

        float bx = lx[0], by = ly[0], bz = lz[0];

        for (int j = 0; j < MM; ++j) {
            if (t == 0) {
                int o = (b * MM + j) * 3;
                centf[o]    = bx; centf[o + 1] = by; centf[o + 2] = bz;
                outc[o]     = rnd_bf16(bx);
                outc[o + 1] = rnd_bf16(by);
                outc[o + 2] = rnd_bf16(bz);
                akey[(j + 2) & 3] = 0ULL;     // reset future slot (race-free)
            }
            float bd = -1.0f; int bi = 0;
#pragma unroll
            for (int i = 0; i < 16; ++i) {
                float dx = x[i] - bx, dy = y[i] - by, dz = z[i] - bz;
                // exact np order: (dx*dx + dy*dy) + dz*dz, RN, no fma
                float d = __fadd_rn(__fadd_rn(__fmul_rn(dx, dx), __fmul_rn(dy, dy)),
                                    __fmul_rn(dz, dz));
                float md = fminf(mind[i], d);
                mind[i] = md;
                if (md > bd) { bd = md; bi = t + i * 256; }  // strict >: smaller idx
            }
            unsigned int khi = __float_as_uint(bd);
            unsigned int klo = 0xFFFFFFFFu - (unsigned)bi;
            wave_max_key(khi, klo);           // lane 63 of each wave = wave max
            if ((t & 63) == 63)
                atomicMax(&akey[j & 3],
                          ((unsigned long long)khi << 32) | (unsigned long long)klo);
            __syncthreads();
            unsigned long long bk = akey[j & 3];
            int best = (int)(0xFFFFFFFFu - (unsigned)(bk & 0xFFFFFFFFULL));
            bx = lx[best]; by = ly[best]; bz = lz[best];
        }
    } else if (blockIdx.x < BB + (BB * NN) / 256) {
        // ================= featmlp path =================
        float* w1 = smem;
        float* w2 = smem + CIN * CIN;
        for (int i = t; i < CIN * CIN; i += 256) { w1[i] = fw1[i]; w2[i] = fw2[i]; }
        __syncthreads();

        const int gid = (blockIdx.x - BB) * 256 + t;   // b*N + n
        const int b = gid >> 12, n = gid & (NN - 1);
        const float* fp = feat + (size_t)b * CIN * NN + n;

        float f[CIN];
#pragma unroll
        for (int c = 0; c < CIN; ++c) f[c] = fp[(size_t)c * NN];

        float h1[CIN];
        for (int o = 0; o < CIN; ++o) {
            float acc = fb1[o];
#pragma unroll
            for (int c = 0; c < CIN; ++c) acc = fmaf(f[c], w1[o * CIN + c], acc);
            h1[o] = fmaxf(acc, 0.f);
        }
        float h2[CIN];
        for (int o = 0; o < CIN; ++o) {
            float acc = fb2[o];
#pragma unroll
            for (int c = 0; c < CIN; ++c) acc = fmaf(h1[c], w2[o * CIN + c], acc);
            h2[o] = fmaxf(acc, 0.f);
        }
        __hip_bfloat16* op = fout + (size_t)gid * HH;
        for (int o = 0; o < HH; ++o) {
            float acc = fb3[o];
#pragma unroll
            for (int c = 0; c < CIN; ++c) acc = fmaf(h2[c], fw3[o * CIN + c], acc);
            op[o] = __float2bfloat16(acc);
        }
    } else {
        // ================= pw3T transpose (one-time, 32KB) =================
        for (int i = t; i < HH * CIN; i += 256) {
            int o = i >> 6, c = i & 63;       // read coalesced, write scattered
            pw3T[c * HH + o] = pw3[i];
        }
    }
}

// ---------------------------------------------------------------------------
// Kernel 3: fused ball-query + point MLP + max + feature gather-max.
// R18: 256 threads / 4 waves per block (was 64/1). groupnet was ~320us vs
// ~120us issue floor (2.7x latency gap at ~170 VGPR -> 2-3 waves/SIMD).
//  - phase 1 (ball query): wave 0 only, unchanged 4-deep pipeline.
//  - phase 2: all waves compute h1 (redundant, cheap); wave w computes
//    output channels [16w,16w+16) -- per-channel fma chains bit-identical.
//  - phase 3: wave w handles k in [16w,16w+16), TWO passes over channel
//    halves (peak w3 regs 128->64); weights read COALESCED from pw3T;
//    h2s reads are wave-uniform broadcasts (conflict-free). Partial maxes
//    merged via LDS + fmax (associative -> bit-exact).
//  - phase 4: k-split likewise; partials merged in LDS.
// h2 bf16-rounding (phase 2/3) adds ~0.013 abs error to point-path outputs
// (threshold >= 0.05) -- discrete selections and feature path untouched.
// ---------------------------------------------------------------------------
#define H2SU 36   // u32 stride per k-row (32 data + 4 pad, 16B aligned)
__global__ __launch_bounds__(256, 4) void groupnet_kernel(
    const float* __restrict__ pts,             // [B,3,N] f32
    const float* __restrict__ centf,           // ws [B,M,3] f32
    const __hip_bfloat16* __restrict__ fout,   // ws [B,N,HH] bf16
    const float* __restrict__ pw1, const float* __restrict__ pb1,
    const float* __restrict__ pw2, const float* __restrict__ pb2,
    const float* __restrict__ pw3T, const float* __restrict__ pb3,
    float* __restrict__ outf)                  // d_out + B*M*3: [B,256,M] f32
{
    __shared__ unsigned int h2s[KK * H2SU];    // packed bf16 pairs, 9.2KB
    __shared__ int sels[KK];
    __shared__ float part[4][4][64];           // [wave][pa,pb,flo,fhi][lane]

    const int g = blockIdx.x;                  // b*M + m
    const int b = g >> 10, m = g & (MM - 1);
    const int t = threadIdx.x;
    const int w = t >> 6, lane = t & 63;

    const float* pts_b = pts + (size_t)b * 3 * NN;
    const float cx = centf[(size_t)g * 3];
    const float cy = centf[(size_t)g * 3 + 1];
    const float cz = centf[(size_t)g * 3 + 2];

    // ---- 1) ball query (wave 0 only): 4-deep software pipeline ----
    if (w == 0) {
        int cnt = 0, first = 0;
        bool have_first = false;
        float fx[4], fy[4], fz[4];
#pragma unroll
        for (int q = 0; q < 4; ++q) {
            int p = q * 64 + lane;
            fx[q] = pts_b[p]; fy[q] = pts_b[NN + p]; fz[q] = pts_b[2 * NN + p];
        }
        for (int base = 0; base < NN; base += 256) {
#pragma unroll
            for (int q = 0; q < 4; ++q) {      // q static: regs stay in VGPRs
                const int cb = base + q * 64;
                float vx = fx[q], vy = fy[q], vz = fz[q];
                const int pre = cb + 256 + lane;
                if (pre < NN) {
                    fx[q] = pts_b[pre]; fy[q] = pts_b[NN + pre]; fz[q] = pts_b[2 * NN + pre];
                }
                float dx = vx - cx, dy = vy - cy, dz = vz - cz;
                float d2 = __fadd_rn(__fadd_rn(__fmul_rn(dx, dx), __fmul_rn(dy, dy)),
                                     __fmul_rn(dz, dz));
                bool in = (d2 <= R2F);
                unsigned long long mask = __ballot(in);
                if (!have_first && mask != 0ULL) {
                    first = cb + (int)__builtin_ctzll(mask);
                    have_first = true;
                }
                int pos = cnt + (int)__popcll(mask & ((1ULL << lane) - 1ULL));
                if (in && pos < KK) sels[pos] = cb + lane;
                cnt += (int)__popcll(mask);
            }
        }
        if (cnt < KK) {
            for (int q = cnt + lane; q < KK; q += 64) sels[q] = first;
        }
    }
    __syncthreads();                           // sels visible

    float* ob = outf + (size_t)b * 256 * MM + m;

    // ---- 2) point layers 1-2: lane = slot k; wave w -> channels [16w,16w+16)
    {
        const int s = sels[lane];
        const float x = pts_b[s]          - cx;
        const float y = pts_b[NN + s]     - cy;
        const float z = pts_b[2 * NN + s] - cz;
        float h1[CIN];
#pragma unroll
        for (int o = 0; o < CIN; ++o) {
            float acc = pb1[o];
            acc = fmaf(x, pw1[o * 3 + 0], acc);
            acc = fmaf(y, pw1[o * 3 + 1], acc);
            acc = fmaf(z, pw1[o * 3 + 2], acc);
            h1[o] = fmaxf(acc, 0.f);
        }
        for (int o8 = 0; o8 < 2; ++o8) {       // 8 outputs per iter, 16 total
            const int ob0 = w * 16 + o8 * 8;
            float a[8];
#pragma unroll
            for (int q = 0; q < 8; ++q) a[q] = pb2[ob0 + q];
            for (int c = 0; c < CIN; ++c) {
                float hc = h1[c];
#pragma unroll
                for (int q = 0; q < 8; ++q)
                    a[q] = fmaf(hc, pw2[(ob0 + q) * CIN + c], a[q]);
            }
            uint4 pk;
            pk.x = bf16bits(fmaxf(a[0], 0.f)) | (bf16bits(fmaxf(a[1], 0.f)) << 16);
            pk.y = bf16bits(fmaxf(a[2], 0.f)) | (bf16bits(fmaxf(a[3], 0.f)) << 16);
            pk.z = bf16bits(fmaxf(a[4], 0.f)) | (bf16bits(fmaxf(a[5], 0.f)) << 16);
            pk.w = bf16bits(fmaxf(a[6], 0.f)) | (bf16bits(fmaxf(a[7], 0.f)) << 16);
            *(uint4*)&h2s[lane * H2SU + w * 8 + o8 * 4] = pk;
        }
    }
    __syncthreads();                           // h2s complete

    // ---- 3) point layer 3 + k-partial max; wave w -> k in [16w,16w+16) ----
    {
        const int k0 = w * 16;
        float wv[CIN];
#pragma unroll 2
        for (int half = 0; half < 2; ++half) { // A: ch lane, B: ch lane+64
            const int ch = half * 64 + lane;
#pragma unroll
            for (int c = 0; c < CIN; ++c) wv[c] = pw3T[c * HH + ch];  // coalesced
            const float bias = pb3[ch];
            float p0 = -3.4e38f, p1 = -3.4e38f;
            for (int kk = 0; kk < 8; ++kk) {   // 2 chains: k0+kk, k0+8+kk
                float v0 = bias, v1 = bias;
#pragma unroll
                for (int u4 = 0; u4 < 8; ++u4) {
                    uint4 q0 = *(const uint4*)&h2s[(k0 + kk) * H2SU + u4 * 4];
                    uint4 q1 = *(const uint4*)&h2s[(k0 + 8 + kk) * H2SU + u4 * 4];
                    const unsigned int* a0 = &q0.x;
                    const unsigned int* a1 = &q1.x;
#pragma unroll
                    for (int jj = 0; jj < 4; ++jj) {
                        int c = u4 * 8 + jj * 2;
                        v0 = fmaf(__uint_as_float(a0[jj] << 16),         wv[c],     v0);
                        v0 = fmaf(__uint_as_float(a0[jj] & 0xFFFF0000u), wv[c + 1], v0);
                        v1 = fmaf(__uint_as_float(a1[jj] << 16),         wv[c],     v1);
                        v1 = fmaf(__uint_as_float(a1[jj] & 0xFFFF0000u), wv[c + 1], v1);
                    }
                }
                p0 = fmaxf(p0, v0); p1 = fmaxf(p1, v1);
            }
            part[w][half][lane] = fmaxf(p0, p1);
        }
    }

    // ---- 4) feature gather-max; wave w -> k in [16w,16w+16) ----
    // lane owns channels (2*lane, 2*lane+1) via u32 bf16-pair loads.
    {
        const __hip_bfloat16* fb_ = fout + (size_t)b * NN * HH;
        const int k0 = w * 16;
        float l0 = -3.4e38f, h0 = -3.4e38f, l1 = -3.4e38f, h1v = -3.4e38f;
        for (int kk = 0; kk < 8; ++kk) {
            unsigned int u0 = ((const unsigned int*)(fb_ + (size_t)sels[k0 + kk]     * HH))[lane];
            unsigned int u1 = ((const unsigned int*)(fb_ + (size_t)sels[k0 + 8 + kk] * HH))[lane];
            l0  = fmaxf(l0,  __uint_as_float(u0 << 16));
            h0  = fmaxf(h0,  __uint_as_float(u0 & 0xFFFF0000u));
            l1  = fmaxf(l1,  __uint_as_float(u1 << 16));
            h1v = fmaxf(h1v, __uint_as_float(u1 & 0xFFFF0000u));
        }
        part[w][2][lane] = fmaxf(l0, l1);
        part[w][3][lane] = fmaxf(h0, h1v);
    }
    __syncthreads();                           // partials visible

    // ---- 5) finalize: wave w merges + writes its output group ----
    {
        const int slot = (w == 0) ? 2 : (w == 1) ? 3 : (w == 2) ? 0 : 1;
        float v = fmaxf(fmaxf(part[0][slot][lane], part[1][slot][lane]),
                        fmaxf(part[2][slot][lane], part[3][slot][lane]));
        if      (w == 0) ob[(size_t)(2 * lane)     * MM] = v;            // feat lo
        else if (w == 1) ob[(size_t)(2 * lane + 1) * MM] = v;            // feat hi
        else if (w == 2) ob[(size_t)(128 + lane)   * MM] = rnd_bf16(v);  // point a
        else             ob[(size_t)(192 + lane)   * MM] = rnd_bf16(v);  // point b
    }
}

extern "C" void kernel_launch(void* const* d_in, const int* in_sizes, int n_in,
                              void* d_out, int out_size, void* d_ws, size_t ws_size,
                              hipStream_t stream) {
    const float* pts  = (const float*)d_in[0];
    const float* feat = (const float*)d_in[1];
    const float* pw1  = (const float*)d_in[2];
    const float* pb1  = (const float*)d_in[3];
    const float* pw2  = (const float*)d_in[4];
    const float* pb2  = (const float*)d_in[5];
    const float* pw3  = (const float*)d_in[6];
    const float* pb3  = (const float*)d_in[7];
    const float* fw1  = (const float*)d_in[8];
    const float* fb1  = (const float*)d_in[9];
    const float* fw2  = (const float*)d_in[10];
    const float* fb2  = (const float*)d_in[11];
    const float* fw3  = (const float*)d_in[12];
    const float* fb3  = (const float*)d_in[13];

    float* out = (float*)d_out;                // f32 output

    // ws: [0,96KB) f32 centroids; [96KB,+8.39MB) bf16 feature-MLP cache;
    // then 32KB pw3T. Total ~8.52MB.
    float* centf = (float*)d_ws;
    __hip_bfloat16* fout = (__hip_bfloat16*)((char*)d_ws + (size_t)BB * MM * 3 * 4);
    float* pw3T = (float*)((char*)d_ws + (size_t)BB * MM * 3 * 4
                           + (size_t)BB * NN * HH * 2);

    // Merged launch: blocks 0..7 = FPS, 8..135 = featmlp, 136 = pw3T
    // transpose (all independent; consumed only by groupnet, stream-ordered).
    fps_featmlp_kernel<<<BB + (BB * NN) / 256 + 1, 256, 0, stream>>>(
        pts, centf, out, feat, fw1, fb1, fw2, fb2, fw3, fb3, fout, pw3, pw3T);
    groupnet_kernel<<<BB * MM, 256, 0, stream>>>(
        pts, centf, fout,
        pw1, pb1, pw2, pb2, pw3T, pb3,
        out + (size_t)BB * MM * 3);
}

// Round 4
// 848.274 us; speedup vs baseline: 1.5980x; 1.5980x over previous
//
#include <hip/hip_runtime.h>
#include <hip/hip_bf16.h>

// Problem constants (B=8, N=4096, M=N/4, K=64, C_in=64, h=128)
#define BB   8
#define NN   4096
#define MM   1024
#define KK   64
#define CIN  64
#define HH   128

// f32 radius^2 predicate: largest f32 <= 0.2*0.2 (f64) = 0x3D23D70A.
#define R2F 0.039999999105930328f

#define NPROD (BB + (BB * NN) / 256)   // 136 producer blocks (8 FPS + 128 featmlp)
#define H2SU  36                        // u32 stride per k-row (32 data + 4 pad)

// Inputs: f32, dict order. Output: f32, values bf16-rounded (matches np ref).
static __device__ __forceinline__ float rnd_bf16(float v) {
    return __bfloat162float(__float2bfloat16(v));
}
// Manual RNE f32->bf16 (finite inputs only; matches RNE for our h2 values).
static __device__ __forceinline__ unsigned int bf16bits(float v) {
    unsigned int u = __float_as_uint(v);
    return (u + 0x7FFFu + ((u >> 16) & 1u)) >> 16;
}
// Wave-local LDS fence: orders this wave's ds writes/reads (lgkmcnt drain +
// compiler barrier). Valid replacement for __syncthreads in a body where
// only ONE wave touches its LDS slice.
static __device__ __forceinline__ void wavefence() {
    __builtin_amdgcn_wave_barrier();
    __threadfence_block();
    __builtin_amdgcn_wave_barrier();
}

// ---------------------------------------------------------------------------
// ONE fused kernel. Blocks 0..7: FPS (EXACT R11 body + progress publish).
// Blocks 8..135: featmlp (+done counter). Blocks 136..2183: 4 independent
// groupnet waves each (R17 64-thr body per wave), spin-waiting on FPS
// progress so grouping overlaps the serial FPS instead of running after it.
//
// FPS ledger: R11 atomic=631 PROVEN FLOOR. R12 512thr=790. R13 slot-split
// =694. R15 ds_permute shuffle=1068. R16 pk-asm+tree+4x64atomic=772.
// R18 DPP wave-reduce=862 (bank-conflicts->0 proved atomic displaced, yet
// SLOWER: 6-step u64-compare DPP chain > 260cy atomic). DO NOT attack the
// atomic again. Groupnet ledger: R17 1-wave-per-group=~320us GOOD;
// R18 4-wave-split=~490 REGRESSED (redundant h1, 2-pass weights, barriers).
//
// Overlap safety: producers are the lowest blockIdx -> resident first; FPS
// never waits on anyone; consumers spin (relaxed poll + s_sleep, acquire on
// exit) on agent-scope flags; release stores publish centf/fout (G16:
// cross-XCD visibility via scoped atomics). flags zeroed by hipMemsetAsync
// before each launch (graph-capture-safe).
// ---------------------------------------------------------------------------
__global__ __launch_bounds__(256, 3) void fused_kernel(
    const float* __restrict__ pts,            // [B,3,N] f32
    float* __restrict__ centf,                // ws [B,M,3] f32 (exact)
    float* __restrict__ outc,                 // d_out (first B*M*3), f32
    const float* __restrict__ feat,           // [B,CIN,N] f32
    const float* __restrict__ fw1, const float* __restrict__ fb1,
    const float* __restrict__ fw2, const float* __restrict__ fb2,
    const float* __restrict__ fw3, const float* __restrict__ fb3,
    __hip_bfloat16* __restrict__ fout,        // ws [B,N,HH] bf16
    const float* __restrict__ pw1, const float* __restrict__ pb1,
    const float* __restrict__ pw2, const float* __restrict__ pb2,
    const float* __restrict__ pw3, const float* __restrict__ pb3,
    float* __restrict__ outf,                 // d_out + B*M*3: [B,256,M] f32
    unsigned int* __restrict__ flags)         // ws: [0..7]=progress, [8]=fdone
{
    __shared__ float smem[3 * NN];            // 48KB, overlaid per branch
    __shared__ unsigned long long akey[4];
    const int t = threadIdx.x;

    if (blockIdx.x < BB) {
        // ================= FPS (EXACT R11 body + publish) =================
        const int b = blockIdx.x;
        float* lx = smem;
        float* ly = smem + NN;
        float* lz = smem + 2 * NN;

        const float* px = pts + (size_t)b * 3 * NN;
        float x[16], y[16], z[16], mind[16];
#pragma unroll
        for (int i = 0; i < 16; ++i) {
            int p = t + i * 256;              // coalesced
            x[i] = px[p];
            y[i] = px[NN + p];
            z[i] = px[2 * NN + p];
            lx[p] = x[i]; ly[p] = y[i]; lz[p] = z[i];
            mind[i] = 3.4e38f;
        }
        if (t < 4) akey[t] = 0ULL;
        __syncthreads();

        float bx = lx[0], by = ly[0], bz = lz[0];

        for (int j = 0; j < MM; ++j) {
            if (t == 0) {
                int o = (b * MM + j) * 3;
                centf[o]    = bx; centf[o + 1] = by; centf[o + 2] = bz;
                outc[o]     = rnd_bf16(bx);
                outc[o + 1] = rnd_bf16(by);
                outc[o + 2] = rnd_bf16(bz);
                if ((j & 15) == 15)           // publish centroids [0..j]
                    __hip_atomic_store(&flags[b], (unsigned int)(j + 1),
                                       __ATOMIC_RELEASE, __HIP_MEMORY_SCOPE_AGENT);
                akey[(j + 2) & 3] = 0ULL;     // reset future slot (race-free)
            }
            float bd = -1.0f; int bi = 0;
#pragma unroll
            for (int i = 0; i < 16; ++i) {
                float dx = x[i] - bx, dy = y[i] - by, dz = z[i] - bz;
                // exact np order: (dx*dx + dy*dy) + dz*dz, RN, no fma
                float d = __fadd_rn(__fadd_rn(__fmul_rn(dx, dx), __fmul_rn(dy, dy)),
                                    __fmul_rn(dz, dz));
                float md = fminf(mind[i], d);
                mind[i] = md;
                if (md > bd) { bd = md; bi = t + i * 256; }  // strict >: smaller idx
            }
            unsigned long long key =
                ((unsigned long long)__float_as_uint(bd) << 32) |
                (unsigned long long)(0xFFFFFFFFu - (unsigned)bi);
            atomicMax(&akey[j & 3], key);
            __syncthreads();
            unsigned long long bk = akey[j & 3];
            int best = (int)(0xFFFFFFFFu - (unsigned)(bk & 0xFFFFFFFFULL));
            bx = lx[best]; by = ly[best]; bz = lz[best];
        }
    } else if (blockIdx.x < NPROD) {
        // ================= featmlp path (+ done counter) =================
        float* w1 = smem;
        float* w2 = smem + CIN * CIN;
        for (int i = t; i < CIN * CIN; i += 256) { w1[i] = fw1[i]; w2[i] = fw2[i]; }
        __syncthreads();

        const int gid = (blockIdx.x - BB) * 256 + t;   // b*N + n
        const int b = gid >> 12, n = gid & (NN - 1);
        const float* fp = feat + (size_t)b * CIN * NN + n;

        float f[CIN];
#pragma unroll
        for (int c = 0; c < CIN; ++c) f[c] = fp[(size_t)c * NN];

        float h1[CIN];
        for (int o = 0; o < CIN; ++o) {
            float acc = fb1[o];
#pragma unroll
            for (int c = 0; c < CIN; ++c) acc = fmaf(f[c], w1[o * CIN + c], acc);
            h1[o] = fmaxf(acc, 0.f);
        }
        float h2[CIN];
        for (int o = 0; o < CIN; ++o) {
            float acc = fb2[o];
#pragma unroll
            for (int c = 0; c < CIN; ++c) acc = fmaf(h1[c], w2[o * CIN + c], acc);
            h2[o] = fmaxf(acc, 0.f);
        }
        __hip_bfloat16* op = fout + (size_t)gid * HH;
        for (int o = 0; o < HH; ++o) {
            float acc = fb3[o];
#pragma unroll
            for (int c = 0; c < CIN; ++c) acc = fmaf(h2[c], fw3[o * CIN + c], acc);
            op[o] = __float2bfloat16(acc);
        }
        __threadfence();                      // my fout stores -> agent visible
        __syncthreads();
        if (t == 0)
            __hip_atomic_fetch_add(&flags[8], 1u,
                                   __ATOMIC_RELEASE, __HIP_MEMORY_SCOPE_AGENT);
    } else {
        // ============ groupnet: 4 independent waves per block ============
        const int wv = t >> 6, lane = t & 63;
        unsigned int* h2w = ((unsigned int*)smem) + wv * (KK * H2SU);   // 9.2KB/wave
        int* selw = ((int*)smem) + 4 * (KK * H2SU) + wv * KK;           // 256B/wave

        const int g = (blockIdx.x - NPROD) * 4 + wv;   // b*M + m
        const int b = g >> 10, m = g & (MM - 1);

        // spin until centroid m of batch b is published (relaxed poll,
        // acquire once on exit; s_sleep keeps issue pressure off the CU)
        while (__hip_atomic_load(&flags[b], __ATOMIC_RELAXED,
                                 __HIP_MEMORY_SCOPE_AGENT) <= (unsigned)m)
            __builtin_amdgcn_s_sleep(8);
        (void)__hip_atomic_load(&flags[b], __ATOMIC_ACQUIRE,
                                __HIP_MEMORY_SCOPE_AGENT);

        const float* pts_b = pts + (size_t)b * 3 * NN;
        const float cx = centf[(size_t)g * 3];
        const float cy = centf[(size_t)g * 3 + 1];
        const float cz = centf[(size_t)g * 3 + 2];

        // ---- 1) ball query: 4-deep software pipeline (R17) ----
        int cnt = 0, first = 0;
        bool have_first = false;
        float fx[4], fy[4], fz[4];
#pragma unroll
        for (int q = 0; q < 4; ++q) {
            int p = q * 64 + lane;
            fx[q] = pts_b[p]; fy[q] = pts_b[NN + p]; fz[q] = pts_b[2 * NN + p];
        }
        for (int base = 0; base < NN; base += 256) {
#pragma unroll
            for (int q = 0; q < 4; ++q) {      // q static: regs stay in VGPRs
                const int cb = base + q * 64;
                float vx = fx[q], vy = fy[q], vz = fz[q];
                const int pre = cb + 256 + lane;
                if (pre < NN) {
                    fx[q] = pts_b[pre]; fy[q] = pts_b[NN + pre]; fz[q] = pts_b[2 * NN + pre];
                }
                float dx = vx - cx, dy = vy - cy, dz = vz - cz;
                float d2 = __fadd_rn(__fadd_rn(__fmul_rn(dx, dx), __fmul_rn(dy, dy)),
                                     __fmul_rn(dz, dz));
                bool in = (d2 <= R2F);
                unsigned long long mask = __ballot(in);
                if (!have_first && mask != 0ULL) {
                    first = cb + (int)__builtin_ctzll(mask);
                    have_first = true;
                }
                int pos = cnt + (int)__popcll(mask & ((1ULL << lane) - 1ULL));
                if (in && pos < KK) selw[pos] = cb + lane;
                cnt += (int)__popcll(mask);
            }
        }
        if (cnt < KK) {
            for (int q = cnt + lane; q < KK; q += 64) selw[q] = first;
        }
        wavefence();                           // selw visible within wave

        const int s = selw[lane];
        float* ob = outf + (size_t)b * 256 * MM + m;

        // ---- 2) point layers 1-2 (lane = slot k); 8 parallel chains ----
        {
            const float x = pts_b[s]          - cx;
            const float y = pts_b[NN + s]     - cy;
            const float z = pts_b[2 * NN + s] - cz;
            float h1[CIN];
#pragma unroll
            for (int o = 0; o < CIN; ++o) {
                float acc = pb1[o];
                acc = fmaf(x, pw1[o * 3 + 0], acc);
                acc = fmaf(y, pw1[o * 3 + 1], acc);
                acc = fmaf(z, pw1[o * 3 + 2], acc);
                h1[o] = fmaxf(acc, 0.f);
            }
            for (int o8 = 0; o8 < CIN / 8; ++o8) { // 8 outputs per iter
                float a[8];
#pragma unroll
                for (int q = 0; q < 8; ++q) a[q] = pb2[o8 * 8 + q];
                for (int c = 0; c < CIN; ++c) {
                    float hc = h1[c];
#pragma unroll
                    for (int q = 0; q < 8; ++q)
                        a[q] = fmaf(hc, pw2[(o8 * 8 + q) * CIN + c], a[q]);
                }
                uint4 pk;
                pk.x = bf16bits(fmaxf(a[0], 0.f)) | (bf16bits(fmaxf(a[1], 0.f)) << 16);
                pk.y = bf16bits(fmaxf(a[2], 0.f)) | (bf16bits(fmaxf(a[3], 0.f)) << 16);
                pk.z = bf16bits(fmaxf(a[4], 0.f)) | (bf16bits(fmaxf(a[5], 0.f)) << 16);
                pk.w = bf16bits(fmaxf(a[6], 0.f)) | (bf16bits(fmaxf(a[7], 0.f)) << 16);
                *(uint4*)&h2w[lane * H2SU + o8 * 4] = pk;
            }
        }
        wavefence();                           // h2w complete within wave

        // ---- 3) point layer 3 + group max -> out ch 128..255 (R17) ----
        {
            float w3a[CIN], w3b[CIN];
#pragma unroll
            for (int c = 0; c < CIN; ++c) {
                w3a[c] = pw3[(size_t)lane * CIN + c];
                w3b[c] = pw3[(size_t)(lane + 64) * CIN + c];
            }
            const float b3a = pb3[lane], b3b = pb3[lane + 64];
            float pa0 = -3.4e38f, pb0 = -3.4e38f;  // k in [0,32)
            float pa1 = -3.4e38f, pb1v = -3.4e38f; // k in [32,64)
            for (int k = 0; k < KK / 2; ++k) {
                float va0 = b3a, vb0 = b3b, va1 = b3a, vb1 = b3b;
#pragma unroll
                for (int u4 = 0; u4 < 8; ++u4) {   // 8 uint4 = 32 u32 = 64 bf16
                    uint4 p0 = *(const uint4*)&h2w[k * H2SU + u4 * 4];
                    uint4 p1 = *(const uint4*)&h2w[(k + 32) * H2SU + u4 * 4];
                    const unsigned int* w0 = &p0.x;
                    const unsigned int* w1 = &p1.x;
#pragma unroll
                    for (int jj = 0; jj < 4; ++jj) {
                        int c = u4 * 8 + jj * 2;
                        float h0lo = __uint_as_float(w0[jj] << 16);
                        float h0hi = __uint_as_float(w0[jj] & 0xFFFF0000u);
                        float h1lo = __uint_as_float(w1[jj] << 16);
                        float h1hi = __uint_as_float(w1[jj] & 0xFFFF0000u);
                        va0 = fmaf(h0lo, w3a[c],     va0); vb0 = fmaf(h0lo, w3b[c],     vb0);
                        va1 = fmaf(h1lo, w3a[c],     va1); vb1 = fmaf(h1lo, w3b[c],     vb1);
                        va0 = fmaf(h0hi, w3a[c + 1], va0); vb0 = fmaf(h0hi, w3b[c + 1], vb0);
                        va1 = fmaf(h1hi, w3a[c + 1], va1); vb1 = fmaf(h1hi, w3b[c + 1], vb1);
                    }
                }
                pa0 = fmaxf(pa0, va0); pb0  = fmaxf(pb0,  vb0);
                pa1 = fmaxf(pa1, va1); pb1v = fmaxf(pb1v, vb1);
            }
            ob[(size_t)(128 + lane) * MM] = rnd_bf16(fmaxf(pa0, pa1));
            ob[(size_t)(192 + lane) * MM] = rnd_bf16(fmaxf(pb0, pb1v));
        }

        // ---- 4) feature gather-max; wait for featmlp completion first ----
        while (__hip_atomic_load(&flags[8], __ATOMIC_RELAXED,
                                 __HIP_MEMORY_SCOPE_AGENT) < (unsigned)(NPROD - BB))
            __builtin_amdgcn_s_sleep(8);
        (void)__hip_atomic_load(&flags[8], __ATOMIC_ACQUIRE,
                                __HIP_MEMORY_SCOPE_AGENT);
        {
            const __hip_bfloat16* fb_ = fout + (size_t)b * NN * HH;
            unsigned int pf[4];
#pragma unroll
            for (int q = 0; q < 4; ++q)
                pf[q] = ((const unsigned int*)(fb_ + (size_t)selw[q] * HH))[lane];
            float alo[4], ahi[4];
#pragma unroll
            for (int q = 0; q < 4; ++q) { alo[q] = -3.4e38f; ahi[q] = -3.4e38f; }
            for (int k = 0; k < KK; k += 4) {
#pragma unroll
                for (int q = 0; q < 4; ++q) {  // q static: pf stays in VGPRs
                    unsigned int wversion = pf[q];
                    int nk = k + 4 + q;
                    if (nk < KK)
                        pf[q] = ((const unsigned int*)(fb_ + (size_t)selw[nk] * HH))[lane];
                    alo[q] = fmaxf(alo[q], __uint_as_float(wversion << 16));
                    ahi[q] = fmaxf(ahi[q], __uint_as_float(wversion & 0xFFFF0000u));
                }
            }
            float lo = fmaxf(fmaxf(alo[0], alo[1]), fmaxf(alo[2], alo[3]));
            float hi = fmaxf(fmaxf(ahi[0], ahi[1]), fmaxf(ahi[2], ahi[3]));
            ob[(size_t)(2 * lane) * MM]     = lo;  // values already bf16-exact
            ob[(size_t)(2 * lane + 1) * MM] = hi;
        }
    }
}

extern "C" void kernel_launch(void* const* d_in, const int* in_sizes, int n_in,
                              void* d_out, int out_size, void* d_ws, size_t ws_size,
                              hipStream_t stream) {
    const float* pts  = (const float*)d_in[0];
    const float* feat = (const float*)d_in[1];
    const float* pw1  = (const float*)d_in[2];
    const float* pb1  = (const float*)d_in[3];
    const float* pw2  = (const float*)d_in[4];
    const float* pb2  = (const float*)d_in[5];
    const float* pw3  = (const float*)d_in[6];
    const float* pb3  = (const float*)d_in[7];
    const float* fw1  = (const float*)d_in[8];
    const float* fb1  = (const float*)d_in[9];
    const float* fw2  = (const float*)d_in[10];
    const float* fb2  = (const float*)d_in[11];
    const float* fw3  = (const float*)d_in[12];
    const float* fb3  = (const float*)d_in[13];

    float* out = (float*)d_out;                // f32 output

    // ws: [0,96KB) f32 centroids; [96KB,+8.39MB) bf16 feature-MLP cache;
    // then 64B flags (progress[8] + fdone).
    float* centf = (float*)d_ws;
    __hip_bfloat16* fout = (__hip_bfloat16*)((char*)d_ws + (size_t)BB * MM * 3 * 4);
    unsigned int* flags = (unsigned int*)((char*)d_ws + (size_t)BB * MM * 3 * 4
                                          + (size_t)BB * NN * HH * 2);

    // flags must be zero at kernel start on EVERY launch/replay.
    hipMemsetAsync(flags, 0, 64, stream);

    // One fused launch: 8 FPS + 128 featmlp producers first (resident
    // first -> no deadlock), then 2048 consumer blocks x 4 groupnet waves.
    fused_kernel<<<NPROD + (BB * MM) / 4, 256, 0, stream>>>(
        pts, centf, out, feat, fw1, fb1, fw2, fb2, fw3, fb3, fout,
        pw1, pb1, pw2, pb2, pw3, pb3,
        out + (size_t)BB * MM * 3, flags);
}

// Round 5
// 840.266 us; speedup vs baseline: 1.6132x; 1.0095x over previous
//
#include <hip/hip_runtime.h>
#include <hip/hip_bf16.h>

// Problem constants (B=8, N=4096, M=N/4, K=64, C_in=64, h=128)
#define BB   8
#define NN   4096
#define MM   1024
#define KK   64
#define CIN  64
#define HH   128

// f32 radius^2 predicate: largest f32 <= 0.2*0.2 (f64) = 0x3D23D70A.
#define R2F 0.039999999105930328f

#define NPROD (BB + (BB * NN) / 256)   // 136 producer blocks (8 FPS + 128 featmlp)
#define H2SU  36                        // u32 stride per k-row (32 data + 4 pad)

// Inputs: f32, dict order. Output: f32, values bf16-rounded (matches np ref).
static __device__ __forceinline__ float rnd_bf16(float v) {
    return __bfloat162float(__float2bfloat16(v));
}
// Manual RNE f32->bf16 (finite inputs only; matches RNE for our h2 values).
static __device__ __forceinline__ unsigned int bf16bits(float v) {
    unsigned int u = __float_as_uint(v);
    return (u + 0x7FFFu + ((u >> 16) & 1u)) >> 16;
}
// Wave-local LDS fence: orders this wave's ds writes/reads (lgkmcnt drain +
// compiler barrier). Valid replacement for __syncthreads in a body where
// only ONE wave touches its LDS slice.
static __device__ __forceinline__ void wavefence() {
    __builtin_amdgcn_wave_barrier();
    __threadfence_block();
    __builtin_amdgcn_wave_barrier();
}

// ---------------------------------------------------------------------------
// ONE fused kernel (R19 structure, PROVEN: 848us vs R17's 971).
// Blocks 0..7: FPS (EXACT R11 body + progress publish). Blocks 8..135:
// featmlp (+done counter). Blocks 136..2183: 4 independent groupnet waves
// each, spin-waiting on FPS progress so grouping overlaps the serial FPS.
//
// R20 change: FPS waves run at s_setprio(3); consumers at default 0.
// R19 post-mortem: FPS stretched 637->~800us from issue contention with
// 8 co-resident consumer waves (3 blocks/CU). Consumer drain capacity
// (~17-25 groups/us) >> production rate (12.8/us), so consumers have slack;
// priority returns issue slots to the serial FPS chain (T5 mechanism: works
// exactly when waves on a CU have different roles).
//
// FPS ledger: R11 atomic=631 PROVEN FLOOR. R12 512thr=790. R13 slot-split
// =694. R15 ds_permute shuffle=1068. R16 pk-asm+tree+4x64atomic=772.
// R18 DPP wave-reduce=862. DO NOT attack the atomic again.
// Groupnet ledger: R17 1-wave-per-group GOOD; R18 4-wave-split REGRESSED.
// Overlap ledger: R19 fused+spin WIN (-123us); FPS contention is the
// remaining cost (this round's target).
//
// Overlap safety: producers are the lowest blockIdx -> resident first; FPS
// never waits on anyone; consumers spin (relaxed poll + s_sleep, acquire on
// exit) on agent-scope flags; release stores publish centf/fout (G16).
// flags zeroed by hipMemsetAsync before each launch (graph-capture-safe).
// ---------------------------------------------------------------------------
__global__ __launch_bounds__(256, 3) void fused_kernel(
    const float* __restrict__ pts,            // [B,3,N] f32
    float* __restrict__ centf,                // ws [B,M,3] f32 (exact)
    float* __restrict__ outc,                 // d_out (first B*M*3), f32
    const float* __restrict__ feat,           // [B,CIN,N] f32
    const float* __restrict__ fw1, const float* __restrict__ fb1,
    const float* __restrict__ fw2, const float* __restrict__ fb2,
    const float* __restrict__ fw3, const float* __restrict__ fb3,
    __hip_bfloat16* __restrict__ fout,        // ws [B,N,HH] bf16
    const float* __restrict__ pw1, const float* __restrict__ pb1,
    const float* __restrict__ pw2, const float* __restrict__ pb2,
    const float* __restrict__ pw3, const float* __restrict__ pb3,
    float* __restrict__ outf,                 // d_out + B*M*3: [B,256,M] f32
    unsigned int* __restrict__ flags)         // ws: [0..7]=progress, [8]=fdone
{
    __shared__ float smem[3 * NN];            // 48KB, overlaid per branch
    __shared__ unsigned long long akey[4];
    const int t = threadIdx.x;

    if (blockIdx.x < BB) {
        // ================= FPS (EXACT R11 body + publish) =================
        __builtin_amdgcn_s_setprio(3);        // serial chain: win arbitration
        const int b = blockIdx.x;
        float* lx = smem;
        float* ly = smem + NN;
        float* lz = smem + 2 * NN;

        const float* px = pts + (size_t)b * 3 * NN;
        float x[16], y[16], z[16], mind[16];
#pragma unroll
        for (int i = 0; i < 16; ++i) {
            int p = t + i * 256;              // coalesced
            x[i] = px[p];
            y[i] = px[NN + p];
            z[i] = px[2 * NN + p];
            lx[p] = x[i]; ly[p] = y[i]; lz[p] = z[i];
            mind[i] = 3.4e38f;
        }
        if (t < 4) akey[t] = 0ULL;
        __syncthreads();

        float bx = lx[0], by = ly[0], bz = lz[0];

        for (int j = 0; j < MM; ++j) {
            if (t == 0) {
                int o = (b * MM + j) * 3;
                centf[o]    = bx; centf[o + 1] = by; centf[o + 2] = bz;
                outc[o]     = rnd_bf16(bx);
                outc[o + 1] = rnd_bf16(by);
                outc[o + 2] = rnd_bf16(bz);
                if ((j & 15) == 15)           // publish centroids [0..j]
                    __hip_atomic_store(&flags[b], (unsigned int)(j + 1),
                                       __ATOMIC_RELEASE, __HIP_MEMORY_SCOPE_AGENT);
                akey[(j + 2) & 3] = 0ULL;     // reset future slot (race-free)
            }
            float bd = -1.0f; int bi = 0;
#pragma unroll
            for (int i = 0; i < 16; ++i) {
                float dx = x[i] - bx, dy = y[i] - by, dz = z[i] - bz;
                // exact np order: (dx*dx + dy*dy) + dz*dz, RN, no fma
                float d = __fadd_rn(__fadd_rn(__fmul_rn(dx, dx), __fmul_rn(dy, dy)),
                                    __fmul_rn(dz, dz));
                float md = fminf(mind[i], d);
                mind[i] = md;
                if (md > bd) { bd = md; bi = t + i * 256; }  // strict >: smaller idx
            }
            unsigned long long key =
                ((unsigned long long)__float_as_uint(bd) << 32) |
                (unsigned long long)(0xFFFFFFFFu - (unsigned)bi);
            atomicMax(&akey[j & 3], key);
            __syncthreads();
            unsigned long long bk = akey[j & 3];
            int best = (int)(0xFFFFFFFFu - (unsigned)(bk & 0xFFFFFFFFULL));
            bx = lx[best]; by = ly[best]; bz = lz[best];
        }
    } else if (blockIdx.x < NPROD) {
        // ================= featmlp path (+ done counter) =================
        float* w1 = smem;
        float* w2 = smem + CIN * CIN;
        for (int i = t; i < CIN * CIN; i += 256) { w1[i] = fw1[i]; w2[i] = fw2[i]; }
        __syncthreads();

        const int gid = (blockIdx.x - BB) * 256 + t;   // b*N + n
        const int b = gid >> 12, n = gid & (NN - 1);
        const float* fp = feat + (size_t)b * CIN * NN + n;

        float f[CIN];
#pragma unroll
        for (int c = 0; c < CIN; ++c) f[c] = fp[(size_t)c * NN];

        float h1[CIN];
        for (int o = 0; o < CIN; ++o) {
            float acc = fb1[o];
#pragma unroll
            for (int c = 0; c < CIN; ++c) acc = fmaf(f[c], w1[o * CIN + c], acc);
            h1[o] = fmaxf(acc, 0.f);
        }
        float h2[CIN];
        for (int o = 0; o < CIN; ++o) {
            float acc = fb2[o];
#pragma unroll
            for (int c = 0; c < CIN; ++c) acc = fmaf(h1[c], w2[o * CIN + c], acc);
            h2[o] = fmaxf(acc, 0.f);
        }
        __hip_bfloat16* op = fout + (size_t)gid * HH;
        for (int o = 0; o < HH; ++o) {
            float acc = fb3[o];
#pragma unroll
            for (int c = 0; c < CIN; ++c) acc = fmaf(h2[c], fw3[o * CIN + c], acc);
            op[o] = __float2bfloat16(acc);
        }
        __threadfence();                      // my fout stores -> agent visible
        __syncthreads();
        if (t == 0)
            __hip_atomic_fetch_add(&flags[8], 1u,
                                   __ATOMIC_RELEASE, __HIP_MEMORY_SCOPE_AGENT);
    } else {
        // ============ groupnet: 4 independent waves per block ============
        const int wv = t >> 6, lane = t & 63;
        unsigned int* h2w = ((unsigned int*)smem) + wv * (KK * H2SU);   // 9.2KB/wave
        int* selw = ((int*)smem) + 4 * (KK * H2SU) + wv * KK;           // 256B/wave

        const int g = (blockIdx.x - NPROD) * 4 + wv;   // b*M + m
        const int b = g >> 10, m = g & (MM - 1);

        // spin until centroid m of batch b is published (relaxed poll,
        // acquire once on exit; s_sleep keeps issue pressure off the CU)
        while (__hip_atomic_load(&flags[b], __ATOMIC_RELAXED,
                                 __HIP_MEMORY_SCOPE_AGENT) <= (unsigned)m)
            __builtin_amdgcn_s_sleep(8);
        (void)__hip_atomic_load(&flags[b], __ATOMIC_ACQUIRE,
                                __HIP_MEMORY_SCOPE_AGENT);

        const float* pts_b = pts + (size_t)b * 3 * NN;
        const float cx = centf[(size_t)g * 3];
        const float cy = centf[(size_t)g * 3 + 1];
        const float cz = centf[(size_t)g * 3 + 2];

        // ---- 1) ball query: 4-deep software pipeline (R17) ----
        int cnt = 0, first = 0;
        bool have_first = false;
        float fx[4], fy[4], fz[4];
#pragma unroll
        for (int q = 0; q < 4; ++q) {
            int p = q * 64 + lane;
            fx[q] = pts_b[p]; fy[q] = pts_b[NN + p]; fz[q] = pts_b[2 * NN + p];
        }
        for (int base = 0; base < NN; base += 256) {
#pragma unroll
            for (int q = 0; q < 4; ++q) {      // q static: regs stay in VGPRs
                const int cb = base + q * 64;
                float vx = fx[q], vy = fy[q], vz = fz[q];
                const int pre = cb + 256 + lane;
                if (pre < NN) {
                    fx[q] = pts_b[pre]; fy[q] = pts_b[NN + pre]; fz[q] = pts_b[2 * NN + pre];
                }
                float dx = vx - cx, dy = vy - cy, dz = vz - cz;
                float d2 = __fadd_rn(__fadd_rn(__fmul_rn(dx, dx), __fmul_rn(dy, dy)),
                                     __fmul_rn(dz, dz));
                bool in = (d2 <= R2F);
                unsigned long long mask = __ballot(in);
                if (!have_first && mask != 0ULL) {
                    first = cb + (int)__builtin_ctzll(mask);
                    have_first = true;
                }
                int pos = cnt + (int)__popcll(mask & ((1ULL << lane) - 1ULL));
                if (in && pos < KK) selw[pos] = cb + lane;
                cnt += (int)__popcll(mask);
            }
        }
        if (cnt < KK) {
            for (int q = cnt + lane; q < KK; q += 64) selw[q] = first;
        }
        wavefence();                           // selw visible within wave

        const int s = selw[lane];
        float* ob = outf + (size_t)b * 256 * MM + m;

        // ---- 2) point layers 1-2 (lane = slot k); 8 parallel chains ----
        {
            const float x = pts_b[s]          - cx;
            const float y = pts_b[NN + s]     - cy;
            const float z = pts_b[2 * NN + s] - cz;
            float h1[CIN];
#pragma unroll
            for (int o = 0; o < CIN; ++o) {
                float acc = pb1[o];
                acc = fmaf(x, pw1[o * 3 + 0], acc);
                acc = fmaf(y, pw1[o * 3 + 1], acc);
                acc = fmaf(z, pw1[o * 3 + 2], acc);
                h1[o] = fmaxf(acc, 0.f);
            }
            for (int o8 = 0; o8 < CIN / 8; ++o8) { // 8 outputs per iter
                float a[8];
#pragma unroll
                for (int q = 0; q < 8; ++q) a[q] = pb2[o8 * 8 + q];
                for (int c = 0; c < CIN; ++c) {
                    float hc = h1[c];
#pragma unroll
                    for (int q = 0; q < 8; ++q)
                        a[q] = fmaf(hc, pw2[(o8 * 8 + q) * CIN + c], a[q]);
                }
                uint4 pk;
                pk.x = bf16bits(fmaxf(a[0], 0.f)) | (bf16bits(fmaxf(a[1], 0.f)) << 16);
                pk.y = bf16bits(fmaxf(a[2], 0.f)) | (bf16bits(fmaxf(a[3], 0.f)) << 16);
                pk.z = bf16bits(fmaxf(a[4], 0.f)) | (bf16bits(fmaxf(a[5], 0.f)) << 16);
                pk.w = bf16bits(fmaxf(a[6], 0.f)) | (bf16bits(fmaxf(a[7], 0.f)) << 16);
                *(uint4*)&h2w[lane * H2SU + o8 * 4] = pk;
            }
        }
        wavefence();                           // h2w complete within wave

        // ---- 3) point layer 3 + group max -> out ch 128..255 (R17) ----
        {
            float w3a[CIN], w3b[CIN];
#pragma unroll
            for (int c = 0; c < CIN; ++c) {
                w3a[c] = pw3[(size_t)lane * CIN + c];
                w3b[c] = pw3[(size_t)(lane + 64) * CIN + c];
            }
            const float b3a = pb3[lane], b3b = pb3[lane + 64];
            float pa0 = -3.4e38f, pb0 = -3.4e38f;  // k in [0,32)
            float pa1 = -3.4e38f, pb1v = -3.4e38f; // k in [32,64)
            for (int k = 0; k < KK / 2; ++k) {
                float va0 = b3a, vb0 = b3b, va1 = b3a, vb1 = b3b;
#pragma unroll
                for (int u4 = 0; u4 < 8; ++u4) {   // 8 uint4 = 32 u32 = 64 bf16
                    uint4 p0 = *(const uint4*)&h2w[k * H2SU + u4 * 4];
                    uint4 p1 = *(const uint4*)&h2w[(k + 32) * H2SU + u4 * 4];
                    const unsigned int* w0 = &p0.x;
                    const unsigned int* w1 = &p1.x;
#pragma unroll
                    for (int jj = 0; jj < 4; ++jj) {
                        int c = u4 * 8 + jj * 2;
                        float h0lo = __uint_as_float(w0[jj] << 16);
                        float h0hi = __uint_as_float(w0[jj] & 0xFFFF0000u);
                        float h1lo = __uint_as_float(w1[jj] << 16);
                        float h1hi = __uint_as_float(w1[jj] & 0xFFFF0000u);
                        va0 = fmaf(h0lo, w3a[c],     va0); vb0 = fmaf(h0lo, w3b[c],     vb0);
                        va1 = fmaf(h1lo, w3a[c],     va1); vb1 = fmaf(h1lo, w3b[c],     vb1);
                        va0 = fmaf(h0hi, w3a[c + 1], va0); vb0 = fmaf(h0hi, w3b[c + 1], vb0);
                        va1 = fmaf(h1hi, w3a[c + 1], va1); vb1 = fmaf(h1hi, w3b[c + 1], vb1);
                    }
                }
                pa0 = fmaxf(pa0, va0); pb0  = fmaxf(pb0,  vb0);
                pa1 = fmaxf(pa1, va1); pb1v = fmaxf(pb1v, vb1);
            }
            ob[(size_t)(128 + lane) * MM] = rnd_bf16(fmaxf(pa0, pa1));
            ob[(size_t)(192 + lane) * MM] = rnd_bf16(fmaxf(pb0, pb1v));
        }

        // ---- 4) feature gather-max; wait for featmlp completion first ----
        while (__hip_atomic_load(&flags[8], __ATOMIC_RELAXED,
                                 __HIP_MEMORY_SCOPE_AGENT) < (unsigned)(NPROD - BB))
            __builtin_amdgcn_s_sleep(8);
        (void)__hip_atomic_load(&flags[8], __ATOMIC_ACQUIRE,
                                __HIP_MEMORY_SCOPE_AGENT);
        {
            const __hip_bfloat16* fb_ = fout + (size_t)b * NN * HH;
            unsigned int pf[4];
#pragma unroll
            for (int q = 0; q < 4; ++q)
                pf[q] = ((const unsigned int*)(fb_ + (size_t)selw[q] * HH))[lane];
            float alo[4], ahi[4];
#pragma unroll
            for (int q = 0; q < 4; ++q) { alo[q] = -3.4e38f; ahi[q] = -3.4e38f; }
            for (int k = 0; k < KK; k += 4) {
#pragma unroll
                for (int q = 0; q < 4; ++q) {  // q static: pf stays in VGPRs
                    unsigned int wversion = pf[q];
                    int nk = k + 4 + q;
                    if (nk < KK)
                        pf[q] = ((const unsigned int*)(fb_ + (size_t)selw[nk] * HH))[lane];
                    alo[q] = fmaxf(alo[q], __uint_as_float(wversion << 16));
                    ahi[q] = fmaxf(ahi[q], __uint_as_float(wversion & 0xFFFF0000u));
                }
            }
            float lo = fmaxf(fmaxf(alo[0], alo[1]), fmaxf(alo[2], alo[3]));
            float hi = fmaxf(fmaxf(ahi[0], ahi[1]), fmaxf(ahi[2], ahi[3]));
            ob[(size_t)(2 * lane) * MM]     = lo;  // values already bf16-exact
            ob[(size_t)(2 * lane + 1) * MM] = hi;
        }
    }
}

extern "C" void kernel_launch(void* const* d_in, const int* in_sizes, int n_in,
                              void* d_out, int out_size, void* d_ws, size_t ws_size,
                              hipStream_t stream) {
    const float* pts  = (const float*)d_in[0];
    const float* feat = (const float*)d_in[1];
    const float* pw1  = (const float*)d_in[2];
    const float* pb1  = (const float*)d_in[3];
    const float* pw2  = (const float*)d_in[4];
    const float* pb2  = (const float*)d_in[5];
    const float* pw3  = (const float*)d_in[6];
    const float* pb3  = (const float*)d_in[7];
    const float* fw1  = (const float*)d_in[8];
    const float* fb1  = (const float*)d_in[9];
    const float* fw2  = (const float*)d_in[10];
    const float* fb2  = (const float*)d_in[11];
    const float* fw3  = (const float*)d_in[12];
    const float* fb3  = (const float*)d_in[13];

    float* out = (float*)d_out;                // f32 output

    // ws: [0,96KB) f32 centroids; [96KB,+8.39MB) bf16 feature-MLP cache;
    // then 64B flags (progress[8] + fdone).
    float* centf = (float*)d_ws;
    __hip_bfloat16* fout = (__hip_bfloat16*)((char*)d_ws + (size_t)BB * MM * 3 * 4);
    unsigned int* flags = (unsigned int*)((char*)d_ws + (size_t)BB * MM * 3 * 4
                                          + (size_t)BB * NN * HH * 2);

    // flags must be zero at kernel start on EVERY launch/replay.
    hipMemsetAsync(flags, 0, 64, stream);

    // One fused launch: 8 FPS + 128 featmlp producers first (resident
    // first -> no deadlock), then 2048 consumer blocks x 4 groupnet waves.
    fused_kernel<<<NPROD + (BB * MM) / 4, 256, 0, stream>>>(
        pts, centf, out, feat, fw1, fb1, fw2, fb2, fw3, fb3, fout,
        pw1, pb1, pw2, pb2, pw3, pb3,
        out + (size_t)BB * MM * 3, flags);
}

// Round 7
// 811.134 us; speedup vs baseline: 1.6711x; 1.0359x over previous
//
#include <hip/hip_runtime.h>
#include <hip/hip_bf16.h>

// Problem constants (B=8, N=4096, M=N/4, K=64, C_in=64, h=128)
#define BB   8
#define NN   4096
#define MM   1024
#define KK   64
#define CIN  64
#define HH   128

// f32 radius^2 predicate: largest f32 <= 0.2*0.2 (f64) = 0x3D23D70A.
#define R2F 0.039999999105930328f

#define NPROD (BB + (BB * NN) / 256)   // 136 producer blocks (8 FPS + 128 featmlp)
#define H2SU  36                        // u32 stride per k-row (32 data + 4 pad)
#define SMEMF 21504                     // 86KB LDS -> 1 block/CU (160/86): FPS
                                        // blocks own their CU (R20: setprio
                                        // couldn't fix on-CU contention; this
                                        // removes it by construction)

// Inputs: f32, dict order. Output: f32, values bf16-rounded (matches np ref).
static __device__ __forceinline__ float rnd_bf16(float v) {
    return __bfloat162float(__float2bfloat16(v));
}
// Manual RNE f32->bf16 (finite inputs only; matches RNE for our h2 values).
static __device__ __forceinline__ unsigned int bf16bits(float v) {
    unsigned int u = __float_as_uint(v);
    return (u + 0x7FFFu + ((u >> 16) & 1u)) >> 16;
}
// Wave-local LDS fence: orders this wave's ds writes/reads (lgkmcnt drain +
// compiler barrier). Valid replacement for __syncthreads in a body where
// only ONE wave touches its LDS slice.
static __device__ __forceinline__ void wavefence() {
    __builtin_amdgcn_wave_barrier();
    __threadfence_block();
    __builtin_amdgcn_wave_barrier();
}

// ---------------------------------------------------------------------------
// ONE fused kernel (R19 structure, PROVEN: 848 vs R17's 971).
// Blocks 0..7: FPS (EXACT R11 body + progress publish). Blocks 8..135:
// featmlp (+done counter). Blocks 136..2183: 4 groupnet waves each,
// spin-waiting on FPS progress so grouping overlaps the serial FPS.
//
// R21 changes (resubmitted R22 verbatim -- R21 bench was an infra timeout,
// never executed): (a) LDS padded to 86KB -> 1 block/CU. FPS stretched
// 637->~800 under 2 co-resident consumer blocks (R19); setprio(3) was NULL
// (R20: 804->797, noise) -> contention is LDS-pipe/barrier, not issue
// arbitration. Isolation by occupancy clamp is mechanical, not a hint.
// (b) consumer blocks remapped batch-interleaved (b=idx&7) so the ~120-248
// resident consumer blocks track centroid publication across ALL batches
// (g-sequential would park the window on batch 0's unpublished tail).
// (c) setprio removed (proven inert).
//
// FPS ledger: R11 atomic=631 PROVEN FLOOR. R12 512thr=790. R13 slot-split
// =694. R15 ds_permute=1068. R16 pk-asm+tree=772. R18 DPP=862. R20
// setprio=null. DO NOT attack the atomic or the reduce again.
// Groupnet ledger: R17 1-wave-per-group GOOD; R18 4-wave-split REGRESSED.
// Overlap ledger: R19 fused+spin WIN (-123us).
//
// Overlap safety: producers are the lowest blockIdx -> resident first; FPS
// never waits on anyone; consumers spin (relaxed poll + s_sleep, acquire on
// exit) on agent-scope flags; release stores publish centf/fout (G16).
// flags zeroed by hipMemsetAsync before each launch (graph-capture-safe).
// ---------------------------------------------------------------------------
__global__ __launch_bounds__(256) void fused_kernel(
    const float* __restrict__ pts,            // [B,3,N] f32
    float* __restrict__ centf,                // ws [B,M,3] f32 (exact)
    float* __restrict__ outc,                 // d_out (first B*M*3), f32
    const float* __restrict__ feat,           // [B,CIN,N] f32
    const float* __restrict__ fw1, const float* __restrict__ fb1,
    const float* __restrict__ fw2, const float* __restrict__ fb2,
    const float* __restrict__ fw3, const float* __restrict__ fb3,
    __hip_bfloat16* __restrict__ fout,        // ws [B,N,HH] bf16
    const float* __restrict__ pw1, const float* __restrict__ pb1,
    const float* __restrict__ pw2, const float* __restrict__ pb2,
    const float* __restrict__ pw3, const float* __restrict__ pb3,
    float* __restrict__ outf,                 // d_out + B*M*3: [B,256,M] f32
    unsigned int* __restrict__ flags)         // ws: [0..7]=progress, [8]=fdone
{
    __shared__ float smem[SMEMF];             // 86KB: pad forces 1 block/CU
    __shared__ unsigned long long akey[4];
    const int t = threadIdx.x;

    if (blockIdx.x < BB) {
        // ================= FPS (EXACT R11 body + publish) =================
        const int b = blockIdx.x;
        float* lx = smem;
        float* ly = smem + NN;
        float* lz = smem + 2 * NN;

        const float* px = pts + (size_t)b * 3 * NN;
        float x[16], y[16], z[16], mind[16];
#pragma unroll
        for (int i = 0; i < 16; ++i) {
            int p = t + i * 256;              // coalesced
            x[i] = px[p];
            y[i] = px[NN + p];
            z[i] = px[2 * NN + p];
            lx[p] = x[i]; ly[p] = y[i]; lz[p] = z[i];
            mind[i] = 3.4e38f;
        }
        if (t < 4) akey[t] = 0ULL;
        __syncthreads();

        float bx = lx[0], by = ly[0], bz = lz[0];

        for (int j = 0; j < MM; ++j) {
            if (t == 0) {
                int o = (b * MM + j) * 3;
                centf[o]    = bx; centf[o + 1] = by; centf[o + 2] = bz;
                outc[o]     = rnd_bf16(bx);
                outc[o + 1] = rnd_bf16(by);
                outc[o + 2] = rnd_bf16(bz);
                if ((j & 15) == 15)           // publish centroids [0..j]
                    __hip_atomic_store(&flags[b], (unsigned int)(j + 1),
                                       __ATOMIC_RELEASE, __HIP_MEMORY_SCOPE_AGENT);
                akey[(j + 2) & 3] = 0ULL;     // reset future slot (race-free)
            }
            float bd = -1.0f; int bi = 0;
#pragma unroll
            for (int i = 0; i < 16; ++i) {
                float dx = x[i] - bx, dy = y[i] - by, dz = z[i] - bz;
                // exact np order: (dx*dx + dy*dy) + dz*dz, RN, no fma
                float d = __fadd_rn(__fadd_rn(__fmul_rn(dx, dx), __fmul_rn(dy, dy)),
                                    __fmul_rn(dz, dz));
                float md = fminf(mind[i], d);
                mind[i] = md;
                if (md > bd) { bd = md; bi = t + i * 256; }  // strict >: smaller idx
            }
            unsigned long long key =
                ((unsigned long long)__float_as_uint(bd) << 32) |
                (unsigned long long)(0xFFFFFFFFu - (unsigned)bi);
            atomicMax(&akey[j & 3], key);
            __syncthreads();
            unsigned long long bk = akey[j & 3];
            int best = (int)(0xFFFFFFFFu - (unsigned)(bk & 0xFFFFFFFFULL));
            bx = lx[best]; by = ly[best]; bz = lz[best];
        }
    } else if (blockIdx.x < NPROD) {
        // ================= featmlp path (+ done counter) =================
        float* w1 = smem;
        float* w2 = smem + CIN * CIN;
        for (int i = t; i < CIN * CIN; i += 256) { w1[i] = fw1[i]; w2[i] = fw2[i]; }
        __syncthreads();

        const int gid = (blockIdx.x - BB) * 256 + t;   // b*N + n
        const int b = gid >> 12, n = gid & (NN - 1);
        const float* fp = feat + (size_t)b * CIN * NN + n;

        float f[CIN];
#pragma unroll
        for (int c = 0; c < CIN; ++c) f[c] = fp[(size_t)c * NN];

        float h1[CIN];
        for (int o = 0; o < CIN; ++o) {
            float acc = fb1[o];
#pragma unroll
            for (int c = 0; c < CIN; ++c) acc = fmaf(f[c], w1[o * CIN + c], acc);
            h1[o] = fmaxf(acc, 0.f);
        }
        float h2[CIN];
        for (int o = 0; o < CIN; ++o) {
            float acc = fb2[o];
#pragma unroll
            for (int c = 0; c < CIN; ++c) acc = fmaf(h1[c], w2[o * CIN + c], acc);
            h2[o] = fmaxf(acc, 0.f);
        }
        __hip_bfloat16* op = fout + (size_t)gid * HH;
        for (int o = 0; o < HH; ++o) {
            float acc = fb3[o];
#pragma unroll
            for (int c = 0; c < CIN; ++c) acc = fmaf(h2[c], fw3[o * CIN + c], acc);
            op[o] = __float2bfloat16(acc);
        }
        __threadfence();                      // my fout stores -> agent visible
        __syncthreads();
        if (t == 0)
            __hip_atomic_fetch_add(&flags[8], 1u,
                                   __ATOMIC_RELEASE, __HIP_MEMORY_SCOPE_AGENT);
    } else {
        // ============ groupnet: 4 independent waves per block ============
        // Batch-interleaved mapping: resident window (~120-248 blocks at
        // 1 block/CU) must track publication across ALL 8 batches.
        const int wv = t >> 6, lane = t & 63;
        unsigned int* h2w = ((unsigned int*)smem) + wv * (KK * H2SU);   // 9.2KB/wave
        int* selw = ((int*)smem) + 4 * (KK * H2SU) + wv * KK;           // 256B/wave

        const int idx = blockIdx.x - NPROD;            // 0..2047
        const int b = idx & 7;
        const int m = (idx >> 3) * 4 + wv;             // 0..1023
        const int g = b * MM + m;

        // spin until centroid m of batch b is published (relaxed poll,
        // acquire once on exit; s_sleep keeps issue pressure off the CU)
        while (__hip_atomic_load(&flags[b], __ATOMIC_RELAXED,
                                 __HIP_MEMORY_SCOPE_AGENT) <= (unsigned)m)
            __builtin_amdgcn_s_sleep(8);
        (void)__hip_atomic_load(&flags[b], __ATOMIC_ACQUIRE,
                                __HIP_MEMORY_SCOPE_AGENT);

        const float* pts_b = pts + (size_t)b * 3 * NN;
        const float cx = centf[(size_t)g * 3];
        const float cy = centf[(size_t)g * 3 + 1];
        const float cz = centf[(size_t)g * 3 + 2];

        // ---- 1) ball query: 4-deep software pipeline (R17) ----
        int cnt = 0, first = 0;
        bool have_first = false;
        float fx[4], fy[4], fz[4];
#pragma unroll
        for (int q = 0; q < 4; ++q) {
            int p = q * 64 + lane;
            fx[q] = pts_b[p]; fy[q] = pts_b[NN + p]; fz[q] = pts_b[2 * NN + p];
        }
        for (int base = 0; base < NN; base += 256) {
#pragma unroll
            for (int q = 0; q < 4; ++q) {      // q static: regs stay in VGPRs
                const int cb = base + q * 64;
                float vx = fx[q], vy = fy[q], vz = fz[q];
                const int pre = cb + 256 + lane;
                if (pre < NN) {
                    fx[q] = pts_b[pre]; fy[q] = pts_b[NN + pre]; fz[q] = pts_b[2 * NN + pre];
                }
                float dx = vx - cx, dy = vy - cy, dz = vz - cz;
                float d2 = __fadd_rn(__fadd_rn(__fmul_rn(dx, dx), __fmul_rn(dy, dy)),
                                     __fmul_rn(dz, dz));
                bool in = (d2 <= R2F);
                unsigned long long mask = __ballot(in);
                if (!have_first && mask != 0ULL) {
                    first = cb + (int)__builtin_ctzll(mask);
                    have_first = true;
                }
                int pos = cnt + (int)__popcll(mask & ((1ULL << lane) - 1ULL));
                if (in && pos < KK) selw[pos] = cb + lane;
                cnt += (int)__popcll(mask);
            }
        }
        if (cnt < KK) {
            for (int q = cnt + lane; q < KK; q += 64) selw[q] = first;
        }
        wavefence();                           // selw visible within wave

        const int s = selw[lane];
        float* ob = outf + (size_t)b * 256 * MM + m;

        // ---- 2) point layers 1-2 (lane = slot k); 8 parallel chains ----
        {
            const float x = pts_b[s]          - cx;
            const float y = pts_b[NN + s]     - cy;
            const float z = pts_b[2 * NN + s] - cz;
            float h1[CIN];
#pragma unroll
            for (int o = 0; o < CIN; ++o) {
                float acc = pb1[o];
                acc = fmaf(x, pw1[o * 3 + 0], acc);
                acc = fmaf(y, pw1[o * 3 + 1], acc);
                acc = fmaf(z, pw1[o * 3 + 2], acc);
                h1[o] = fmaxf(acc, 0.f);
            }
            for (int o8 = 0; o8 < CIN / 8; ++o8) { // 8 outputs per iter
                float a[8];
#pragma unroll
                for (int q = 0; q < 8; ++q) a[q] = pb2[o8 * 8 + q];
                for (int c = 0; c < CIN; ++c) {
                    float hc = h1[c];
#pragma unroll
                    for (int q = 0; q < 8; ++q)
                        a[q] = fmaf(hc, pw2[(o8 * 8 + q) * CIN + c], a[q]);
                }
                uint4 pk;
                pk.x = bf16bits(fmaxf(a[0], 0.f)) | (bf16bits(fmaxf(a[1], 0.f)) << 16);
                pk.y = bf16bits(fmaxf(a[2], 0.f)) | (bf16bits(fmaxf(a[3], 0.f)) << 16);
                pk.z = bf16bits(fmaxf(a[4], 0.f)) | (bf16bits(fmaxf(a[5], 0.f)) << 16);
                pk.w = bf16bits(fmaxf(a[6], 0.f)) | (bf16bits(fmaxf(a[7], 0.f)) << 16);
                *(uint4*)&h2w[lane * H2SU + o8 * 4] = pk;
            }
        }
        wavefence();                           // h2w complete within wave

        // ---- 3) point layer 3 + group max -> out ch 128..255 (R17) ----
        {
            float w3a[CIN], w3b[CIN];
#pragma unroll
            for (int c = 0; c < CIN; ++c) {
                w3a[c] = pw3[(size_t)lane * CIN + c];
                w3b[c] = pw3[(size_t)(lane + 64) * CIN + c];
            }
            const float b3a = pb3[lane], b3b = pb3[lane + 64];
            float pa0 = -3.4e38f, pb0 = -3.4e38f;  // k in [0,32)
            float pa1 = -3.4e38f, pb1v = -3.4e38f; // k in [32,64)
            for (int k = 0; k < KK / 2; ++k) {
                float va0 = b3a, vb0 = b3b, va1 = b3a, vb1 = b3b;
#pragma unroll
                for (int u4 = 0; u4 < 8; ++u4) {   // 8 uint4 = 32 u32 = 64 bf16
                    uint4 p0 = *(const uint4*)&h2w[k * H2SU + u4 * 4];
                    uint4 p1 = *(const uint4*)&h2w[(k + 32) * H2SU + u4 * 4];
                    const unsigned int* w0 = &p0.x;
                    const unsigned int* w1 = &p1.x;
#pragma unroll
                    for (int jj = 0; jj < 4; ++jj) {
                        int c = u4 * 8 + jj * 2;
                        float h0lo = __uint_as_float(w0[jj] << 16);
                        float h0hi = __uint_as_float(w0[jj] & 0xFFFF0000u);
                        float h1lo = __uint_as_float(w1[jj] << 16);
                        float h1hi = __uint_as_float(w1[jj] & 0xFFFF0000u);
                        va0 = fmaf(h0lo, w3a[c],     va0); vb0 = fmaf(h0lo, w3b[c],     vb0);
                        va1 = fmaf(h1lo, w3a[c],     va1); vb1 = fmaf(h1lo, w3b[c],     vb1);
                        va0 = fmaf(h0hi, w3a[c + 1], va0); vb0 = fmaf(h0hi, w3b[c + 1], vb0);
                        va1 = fmaf(h1hi, w3a[c + 1], va1); vb1 = fmaf(h1hi, w3b[c + 1], vb1);
                    }
                }
                pa0 = fmaxf(pa0, va0); pb0  = fmaxf(pb0,  vb0);
                pa1 = fmaxf(pa1, va1); pb1v = fmaxf(pb1v, vb1);
            }
            ob[(size_t)(128 + lane) * MM] = rnd_bf16(fmaxf(pa0, pa1));
            ob[(size_t)(192 + lane) * MM] = rnd_bf16(fmaxf(pb0, pb1v));
        }

        // ---- 4) feature gather-max; wait for featmlp completion first ----
        while (__hip_atomic_load(&flags[8], __ATOMIC_RELAXED,
                                 __HIP_MEMORY_SCOPE_AGENT) < (unsigned)(NPROD - BB))
            __builtin_amdgcn_s_sleep(8);
        (void)__hip_atomic_load(&flags[8], __ATOMIC_ACQUIRE,
                                __HIP_MEMORY_SCOPE_AGENT);
        {
            const __hip_bfloat16* fb_ = fout + (size_t)b * NN * HH;
            unsigned int pf[4];
#pragma unroll
            for (int q = 0; q < 4; ++q)
                pf[q] = ((const unsigned int*)(fb_ + (size_t)selw[q] * HH))[lane];
            float alo[4], ahi[4];
#pragma unroll
            for (int q = 0; q < 4; ++q) { alo[q] = -3.4e38f; ahi[q] = -3.4e38f; }
            for (int k = 0; k < KK; k += 4) {
#pragma unroll
                for (int q = 0; q < 4; ++q) {  // q static: pf stays in VGPRs
                    unsigned int wversion = pf[q];
                    int nk = k + 4 + q;
                    if (nk < KK)
                        pf[q] = ((const unsigned int*)(fb_ + (size_t)selw[nk] * HH))[lane];
                    alo[q] = fmaxf(alo[q], __uint_as_float(wversion << 16));
                    ahi[q] = fmaxf(ahi[q], __uint_as_float(wversion & 0xFFFF0000u));
                }
            }
            float lo = fmaxf(fmaxf(alo[0], alo[1]), fmaxf(alo[2], alo[3]));
            float hi = fmaxf(fmaxf(ahi[0], ahi[1]), fmaxf(ahi[2], ahi[3]));
            ob[(size_t)(2 * lane) * MM]     = lo;  // values already bf16-exact
            ob[(size_t)(2 * lane + 1) * MM] = hi;
        }
    }
}

extern "C" void kernel_launch(void* const* d_in, const int* in_sizes, int n_in,
                              void* d_out, int out_size, void* d_ws, size_t ws_size,
                              hipStream_t stream) {
    const float* pts  = (const float*)d_in[0];
    const float* feat = (const float*)d_in[1];
    const float* pw1  = (const float*)d_in[2];
    const float* pb1  = (const float*)d_in[3];
    const float* pw2  = (const float*)d_in[4];
    const float* pb2  = (const float*)d_in[5];
    const float* pw3  = (const float*)d_in[6];
    const float* pb3  = (const float*)d_in[7];
    const float* fw1  = (const float*)d_in[8];
    const float* fb1  = (const float*)d_in[9];
    const float* fw2  = (const float*)d_in[10];
    const float* fb2  = (const float*)d_in[11];
    const float* fw3  = (const float*)d_in[12];
    const float* fb3  = (const float*)d_in[13];

    float* out = (float*)d_out;                // f32 output

    // ws: [0,96KB) f32 centroids; [96KB,+8.39MB) bf16 feature-MLP cache;
    // then 64B flags (progress[8] + fdone).
    float* centf = (float*)d_ws;
    __hip_bfloat16* fout = (__hip_bfloat16*)((char*)d_ws + (size_t)BB * MM * 3 * 4);
    unsigned int* flags = (unsigned int*)((char*)d_ws + (size_t)BB * MM * 3 * 4
                                          + (size_t)BB * NN * HH * 2);

    // flags must be zero at kernel start on EVERY launch/replay.
    hipMemsetAsync(flags, 0, 64, stream);

    // One fused launch: 8 FPS + 128 featmlp producers first (resident
    // first -> no deadlock), then 2048 consumer blocks x 4 groupnet waves.
    fused_kernel<<<NPROD + (BB * MM) / 4, 256, 0, stream>>>(
        pts, centf, out, feat, fw1, fb1, fw2, fb2, fw3, fb3, fout,
        pw1, pb1, pw2, pb2, pw3, pb3,
        out + (size_t)BB * MM * 3, flags);
}

// Round 8
// 811.020 us; speedup vs baseline: 1.6714x; 1.0001x over previous
//
#include <hip/hip_runtime.h>
#include <hip/hip_bf16.h>

// Problem constants (B=8, N=4096, M=N/4, K=64, C_in=64, h=128)
#define BB   8
#define NN   4096
#define MM   1024
#define KK   64
#define CIN  64
#define HH   128

// f32 radius^2 predicate: largest f32 <= 0.2*0.2 (f64) = 0x3D23D70A.
#define R2F 0.039999999105930328f

#define NPROD (BB + (BB * NN) / 256)   // 136 producer blocks (8 FPS + 128 featmlp)
#define H2SU  36                        // u32 stride per k-row (32 data + 4 pad)
#define SMEMF 21504                     // 86KB LDS -> 1 block/CU: FPS isolation
#define FLG(b) ((b) * 16)               // flags padded to one 64B line each
#define FDONE  128                      // featmlp done counter index

// Inputs: f32, dict order. Output: f32, values bf16-rounded (matches np ref).
static __device__ __forceinline__ float rnd_bf16(float v) {
    return __bfloat162float(__float2bfloat16(v));
}
// Manual RNE f32->bf16 (finite inputs only; matches RNE for our h2 values).
static __device__ __forceinline__ unsigned int bf16bits(float v) {
    unsigned int u = __float_as_uint(v);
    return (u + 0x7FFFu + ((u >> 16) & 1u)) >> 16;
}
// Wave-local LDS fence: orders this wave's ds writes/reads.
static __device__ __forceinline__ void wavefence() {
    __builtin_amdgcn_wave_barrier();
    __threadfence_block();
    __builtin_amdgcn_wave_barrier();
}

// ---------------------------------------------------------------------------
// ONE fused kernel. Blocks 0..7: FPS. 8..135: featmlp. 136..2183: 4 groupnet
// waves each, spin-waiting on FPS progress (R19 overlap, PROVEN -123us).
//
// R23 changes: (a) FPS output stores BATCHED. R22 post-mortem: 1-block/CU
// isolation recovered only 40 of the 160us stretch -> residual is the
// per-iter t==0 global stores whose vmcnt(0) drain (before s_barrier) pays
// a store-ack RTT into an L2 congested by consumer traffic, every one of
// 1024 iterations. Now: centroid -> 48-float LDS ring (no vmcnt); every 16
// iters threads t<96 flush 16 centroids to centf/outc after the barrier;
// drain amortized 16x and overlapped with next-iter compute. Publication
// moved to (j&15)==1 with value j-1 (one barrier AFTER the flush's drain
// barrier -> all flush stores are in L2 before the release, preserving the
// ordering proven in R19-R22). Final publish after a trailing syncthreads.
// (b) flags padded to 64B/line (992 polling waves no longer converge on one
// L2 line) + two-tier s_sleep backoff.
//
// FPS ledger: R11 atomic=631 floor(solo). R12 512thr=790. R13 slot-split=694.
// R15 ds_permute=1068. R16 pk+tree=772. R18 DPP=862. R20 setprio=null.
// R22 1blk/CU=758 fused (-40). DO NOT attack the atomic/reduce again.
// Groupnet ledger: R17 1-wave-per-group GOOD; R18 4-wave-split REGRESSED.
// ---------------------------------------------------------------------------
__global__ __launch_bounds__(256) void fused_kernel(
    const float* __restrict__ pts,            // [B,3,N] f32
    float* __restrict__ centf,                // ws [B,M,3] f32 (exact)
    float* __restrict__ outc,                 // d_out (first B*M*3), f32
    const float* __restrict__ feat,           // [B,CIN,N] f32
    const float* __restrict__ fw1, const float* __restrict__ fb1,
    const float* __restrict__ fw2, const float* __restrict__ fb2,
    const float* __restrict__ fw3, const float* __restrict__ fb3,
    __hip_bfloat16* __restrict__ fout,        // ws [B,N,HH] bf16
    const float* __restrict__ pw1, const float* __restrict__ pb1,
    const float* __restrict__ pw2, const float* __restrict__ pb2,
    const float* __restrict__ pw3, const float* __restrict__ pb3,
    float* __restrict__ outf,                 // d_out + B*M*3: [B,256,M] f32
    unsigned int* __restrict__ flags)         // ws: padded progress + fdone
{
    __shared__ float smem[SMEMF];             // 86KB: pad forces 1 block/CU
    __shared__ unsigned long long akey[4];
    __shared__ float lsbuf[48];               // FPS: 16-centroid store ring
    const int t = threadIdx.x;

    if (blockIdx.x < BB) {
        // ================= FPS (R11 body + batched stores) =================
        const int b = blockIdx.x;
        float* lx = smem;
        float* ly = smem + NN;
        float* lz = smem + 2 * NN;

        const float* px = pts + (size_t)b * 3 * NN;
        float x[16], y[16], z[16], mind[16];
#pragma unroll
        for (int i = 0; i < 16; ++i) {
            int p = t + i * 256;              // coalesced
            x[i] = px[p];
            y[i] = px[NN + p];
            z[i] = px[2 * NN + p];
            lx[p] = x[i]; ly[p] = y[i]; lz[p] = z[i];
            mind[i] = 3.4e38f;
        }
        if (t < 4) akey[t] = 0ULL;
        __syncthreads();

        float bx = lx[0], by = ly[0], bz = lz[0];

        for (int j = 0; j < MM; ++j) {
            if (t == 0) {
                lsbuf[(j & 15) * 3 + 0] = bx; // LDS ring: no global store here
                lsbuf[(j & 15) * 3 + 1] = by;
                lsbuf[(j & 15) * 3 + 2] = bz;
                if ((j & 15) == 1 && j > 16)  // flush j-17..j-2 drained by now
                    __hip_atomic_store(&flags[FLG(b)], (unsigned int)(j - 1),
                                       __ATOMIC_RELEASE, __HIP_MEMORY_SCOPE_AGENT);
                akey[(j + 2) & 3] = 0ULL;     // reset future slot (race-free)
            }
            float bd = -1.0f; int bi = 0;
#pragma unroll
            for (int i = 0; i < 16; ++i) {
                float dx = x[i] - bx, dy = y[i] - by, dz = z[i] - bz;
                // exact np order: (dx*dx + dy*dy) + dz*dz, RN, no fma
                float d = __fadd_rn(__fadd_rn(__fmul_rn(dx, dx), __fmul_rn(dy, dy)),
                                    __fmul_rn(dz, dz));
                float md = fminf(mind[i], d);
                mind[i] = md;
                if (md > bd) { bd = md; bi = t + i * 256; }  // strict >: smaller idx
            }
            unsigned long long key =
                ((unsigned long long)__float_as_uint(bd) << 32) |
                (unsigned long long)(0xFFFFFFFFu - (unsigned)bi);
            atomicMax(&akey[j & 3], key);
            __syncthreads();
            if ((j & 15) == 15) {             // flush centroids j-15..j
                const int base = (b * MM + (j - 15)) * 3;
                if (t < 48)       centf[base + t]      = lsbuf[t];
                else if (t < 96)  outc[base + (t - 48)] = rnd_bf16(lsbuf[t - 48]);
            }
            unsigned long long bk = akey[j & 3];
            int best = (int)(0xFFFFFFFFu - (unsigned)(bk & 0xFFFFFFFFULL));
            bx = lx[best]; by = ly[best]; bz = lz[best];
        }
        __syncthreads();                      // drain final flush stores
        if (t == 0)
            __hip_atomic_store(&flags[FLG(b)], (unsigned int)MM,
                               __ATOMIC_RELEASE, __HIP_MEMORY_SCOPE_AGENT);
    } else if (blockIdx.x < NPROD) {
        // ================= featmlp path (+ done counter) =================
        float* w1 = smem;
        float* w2 = smem + CIN * CIN;
        for (int i = t; i < CIN * CIN; i += 256) { w1[i] = fw1[i]; w2[i] = fw2[i]; }
        __syncthreads();

        const int gid = (blockIdx.x - BB) * 256 + t;   // b*N + n
        const int b = gid >> 12, n = gid & (NN - 1);
        const float* fp = feat + (size_t)b * CIN * NN + n;

        float f[CIN];
#pragma unroll
        for (int c = 0; c < CIN; ++c) f[c] = fp[(size_t)c * NN];

        float h1[CIN];
        for (int o = 0; o < CIN; ++o) {
            float acc = fb1[o];
#pragma unroll
            for (int c = 0; c < CIN; ++c) acc = fmaf(f[c], w1[o * CIN + c], acc);
            h1[o] = fmaxf(acc, 0.f);
        }
        float h2[CIN];
        for (int o = 0; o < CIN; ++o) {
            float acc = fb2[o];
#pragma unroll
            for (int c = 0; c < CIN; ++c) acc = fmaf(h1[c], w2[o * CIN + c], acc);
            h2[o] = fmaxf(acc, 0.f);
        }
        __hip_bfloat16* op = fout + (size_t)gid * HH;
        for (int o = 0; o < HH; ++o) {
            float acc = fb3[o];
#pragma unroll
            for (int c = 0; c < CIN; ++c) acc = fmaf(h2[c], fw3[o * CIN + c], acc);
            op[o] = __float2bfloat16(acc);
        }
        __threadfence();                      // my fout stores -> agent visible
        __syncthreads();
        if (t == 0)
            __hip_atomic_fetch_add(&flags[FDONE], 1u,
                                   __ATOMIC_RELEASE, __HIP_MEMORY_SCOPE_AGENT);
    } else {
        // ============ groupnet: 4 independent waves per block ============
        // Batch-interleaved mapping: resident window tracks all 8 batches.
        const int wv = t >> 6, lane = t & 63;
        unsigned int* h2w = ((unsigned int*)smem) + wv * (KK * H2SU);   // 9.2KB/wave
        int* selw = ((int*)smem) + 4 * (KK * H2SU) + wv * KK;           // 256B/wave

        const int idx = blockIdx.x - NPROD;            // 0..2047
        const int b = idx & 7;
        const int m = (idx >> 3) * 4 + wv;             // 0..1023
        const int g = b * MM + m;

        // spin until centroid m of batch b is published (relaxed poll with
        // two-tier backoff; acquire once on exit)
        {
            unsigned int prog;
            while ((prog = __hip_atomic_load(&flags[FLG(b)], __ATOMIC_RELAXED,
                                             __HIP_MEMORY_SCOPE_AGENT)) <= (unsigned)m) {
                if ((unsigned)m - prog > 128u) __builtin_amdgcn_s_sleep(64);
                else                           __builtin_amdgcn_s_sleep(8);
            }
            (void)__hip_atomic_load(&flags[FLG(b)], __ATOMIC_ACQUIRE,
                                    __HIP_MEMORY_SCOPE_AGENT);
        }

        const float* pts_b = pts + (size_t)b * 3 * NN;
        const float cx = centf[(size_t)g * 3];
        const float cy = centf[(size_t)g * 3 + 1];
        const float cz = centf[(size_t)g * 3 + 2];

        // ---- 1) ball query: 4-deep software pipeline (R17) ----
        int cnt = 0, first = 0;
        bool have_first = false;
        float fx[4], fy[4], fz[4];
#pragma unroll
        for (int q = 0; q < 4; ++q) {
            int p = q * 64 + lane;
            fx[q] = pts_b[p]; fy[q] = pts_b[NN + p]; fz[q] = pts_b[2 * NN + p];
        }
        for (int base = 0; base < NN; base += 256) {
#pragma unroll
            for (int q = 0; q < 4; ++q) {      // q static: regs stay in VGPRs
                const int cb = base + q * 64;
                float vx = fx[q], vy = fy[q], vz = fz[q];
                const int pre = cb + 256 + lane;
                if (pre < NN) {
                    fx[q] = pts_b[pre]; fy[q] = pts_b[NN + pre]; fz[q] = pts_b[2 * NN + pre];
                }
                float dx = vx - cx, dy = vy - cy, dz = vz - cz;
                float d2 = __fadd_rn(__fadd_rn(__fmul_rn(dx, dx), __fmul_rn(dy, dy)),
                                     __fmul_rn(dz, dz));
                bool in = (d2 <= R2F);
                unsigned long long mask = __ballot(in);
                if (!have_first && mask != 0ULL) {
                    first = cb + (int)__builtin_ctzll(mask);
                    have_first = true;
                }
                int pos = cnt + (int)__popcll(mask & ((1ULL << lane) - 1ULL));
                if (in && pos < KK) selw[pos] = cb + lane;
                cnt += (int)__popcll(mask);
            }
        }
        if (cnt < KK) {
            for (int q = cnt + lane; q < KK; q += 64) selw[q] = first;
        }
        wavefence();                           // selw visible within wave

        const int s = selw[lane];
        float* ob = outf + (size_t)b * 256 * MM + m;

        // ---- 2) point layers 1-2 (lane = slot k); 8 parallel chains ----
        {
            const float x = pts_b[s]          - cx;
            const float y = pts_b[NN + s]     - cy;
            const float z = pts_b[2 * NN + s] - cz;
            float h1[CIN];
#pragma unroll
            for (int o = 0; o < CIN; ++o) {
                float acc = pb1[o];
                acc = fmaf(x, pw1[o * 3 + 0], acc);
                acc = fmaf(y, pw1[o * 3 + 1], acc);
                acc = fmaf(z, pw1[o * 3 + 2], acc);
                h1[o] = fmaxf(acc, 0.f);
            }
            for (int o8 = 0; o8 < CIN / 8; ++o8) { // 8 outputs per iter
                float a[8];
#pragma unroll
                for (int q = 0; q < 8; ++q) a[q] = pb2[o8 * 8 + q];
                for (int c = 0; c < CIN; ++c) {
                    float hc = h1[c];
#pragma unroll
                    for (int q = 0; q < 8; ++q)
                        a[q] = fmaf(hc, pw2[(o8 * 8 + q) * CIN + c], a[q]);
                }
                uint4 pk;
                pk.x = bf16bits(fmaxf(a[0], 0.f)) | (bf16bits(fmaxf(a[1], 0.f)) << 16);
                pk.y = bf16bits(fmaxf(a[2], 0.f)) | (bf16bits(fmaxf(a[3], 0.f)) << 16);
                pk.z = bf16bits(fmaxf(a[4], 0.f)) | (bf16bits(fmaxf(a[5], 0.f)) << 16);
                pk.w = bf16bits(fmaxf(a[6], 0.f)) | (bf16bits(fmaxf(a[7], 0.f)) << 16);
                *(uint4*)&h2w[lane * H2SU + o8 * 4] = pk;
            }
        }
        wavefence();                           // h2w complete within wave

        // ---- 3) point layer 3 + group max -> out ch 128..255 (R17) ----
        {
            float w3a[CIN], w3b[CIN];
#pragma unroll
            for (int c = 0; c < CIN; ++c) {
                w3a[c] = pw3[(size_t)lane * CIN + c];
                w3b[c] = pw3[(size_t)(lane + 64) * CIN + c];
            }
            const float b3a = pb3[lane], b3b = pb3[lane + 64];
            float pa0 = -3.4e38f, pb0 = -3.4e38f;  // k in [0,32)
            float pa1 = -3.4e38f, pb1v = -3.4e38f; // k in [32,64)
            for (int k = 0; k < KK / 2; ++k) {
                float va0 = b3a, vb0 = b3b, va1 = b3a, vb1 = b3b;
#pragma unroll
                for (int u4 = 0; u4 < 8; ++u4) {   // 8 uint4 = 32 u32 = 64 bf16
                    uint4 p0 = *(const uint4*)&h2w[k * H2SU + u4 * 4];
                    uint4 p1 = *(const uint4*)&h2w[(k + 32) * H2SU + u4 * 4];
                    const unsigned int* w0 = &p0.x;
                    const unsigned int* w1 = &p1.x;
#pragma unroll
                    for (int jj = 0; jj < 4; ++jj) {
                        int c = u4 * 8 + jj * 2;
                        float h0lo = __uint_as_float(w0[jj] << 16);
                        float h0hi = __uint_as_float(w0[jj] & 0xFFFF0000u);
                        float h1lo = __uint_as_float(w1[jj] << 16);
                        float h1hi = __uint_as_float(w1[jj] & 0xFFFF0000u);
                        va0 = fmaf(h0lo, w3a[c],     va0); vb0 = fmaf(h0lo, w3b[c],     vb0);
                        va1 = fmaf(h1lo, w3a[c],     va1); vb1 = fmaf(h1lo, w3b[c],     vb1);
                        va0 = fmaf(h0hi, w3a[c + 1], va0); vb0 = fmaf(h0hi, w3b[c + 1], vb0);
                        va1 = fmaf(h1hi, w3a[c + 1], va1); vb1 = fmaf(h1hi, w3b[c + 1], vb1);
                    }
                }
                pa0 = fmaxf(pa0, va0); pb0  = fmaxf(pb0,  vb0);
                pa1 = fmaxf(pa1, va1); pb1v = fmaxf(pb1v, vb1);
            }
            ob[(size_t)(128 + lane) * MM] = rnd_bf16(fmaxf(pa0, pa1));
            ob[(size_t)(192 + lane) * MM] = rnd_bf16(fmaxf(pb0, pb1v));
        }

        // ---- 4) feature gather-max; wait for featmlp completion first ----
        while (__hip_atomic_load(&flags[FDONE], __ATOMIC_RELAXED,
                                 __HIP_MEMORY_SCOPE_AGENT) < (unsigned)(NPROD - BB))
            __builtin_amdgcn_s_sleep(8);
        (void)__hip_atomic_load(&flags[FDONE], __ATOMIC_ACQUIRE,
                                __HIP_MEMORY_SCOPE_AGENT);
        {
            const __hip_bfloat16* fb_ = fout + (size_t)b * NN * HH;
            unsigned int pf[4];
#pragma unroll
            for (int q = 0; q < 4; ++q)
                pf[q] = ((const unsigned int*)(fb_ + (size_t)selw[q] * HH))[lane];
            float alo[4], ahi[4];
#pragma unroll
            for (int q = 0; q < 4; ++q) { alo[q] = -3.4e38f; ahi[q] = -3.4e38f; }
            for (int k = 0; k < KK; k += 4) {
#pragma unroll
                for (int q = 0; q < 4; ++q) {  // q static: pf stays in VGPRs
                    unsigned int wversion = pf[q];
                    int nk = k + 4 + q;
                    if (nk < KK)
                        pf[q] = ((const unsigned int*)(fb_ + (size_t)selw[nk] * HH))[lane];
                    alo[q] = fmaxf(alo[q], __uint_as_float(wversion << 16));
                    ahi[q] = fmaxf(ahi[q], __uint_as_float(wversion & 0xFFFF0000u));
                }
            }
            float lo = fmaxf(fmaxf(alo[0], alo[1]), fmaxf(alo[2], alo[3]));
            float hi = fmaxf(fmaxf(ahi[0], ahi[1]), fmaxf(ahi[2], ahi[3]));
            ob[(size_t)(2 * lane) * MM]     = lo;  // values already bf16-exact
            ob[(size_t)(2 * lane + 1) * MM] = hi;
        }
    }
}

extern "C" void kernel_launch(void* const* d_in, const int* in_sizes, int n_in,
                              void* d_out, int out_size, void* d_ws, size_t ws_size,
                              hipStream_t stream) {
    const float* pts  = (const float*)d_in[0];
    const float* feat = (const float*)d_in[1];
    const float* pw1  = (const float*)d_in[2];
    const float* pb1  = (const float*)d_in[3];
    const float* pw2  = (const float*)d_in[4];
    const float* pb2  = (const float*)d_in[5];
    const float* pw3  = (const float*)d_in[6];
    const float* pb3  = (const float*)d_in[7];
    const float* fw1  = (const float*)d_in[8];
    const float* fb1  = (const float*)d_in[9];
    const float* fw2  = (const float*)d_in[10];
    const float* fb2  = (const float*)d_in[11];
    const float* fw3  = (const float*)d_in[12];
    const float* fb3  = (const float*)d_in[13];

    float* out = (float*)d_out;                // f32 output

    // ws: [0,96KB) f32 centroids; [96KB,+8.39MB) bf16 feature-MLP cache;
    // then 1KB padded flags (8 progress lines + fdone).
    float* centf = (float*)d_ws;
    __hip_bfloat16* fout = (__hip_bfloat16*)((char*)d_ws + (size_t)BB * MM * 3 * 4);
    unsigned int* flags = (unsigned int*)((char*)d_ws + (size_t)BB * MM * 3 * 4
                                          + (size_t)BB * NN * HH * 2);

    // flags must be zero at kernel start on EVERY launch/replay.
    hipMemsetAsync(flags, 0, 1024, stream);

    // One fused launch: 8 FPS + 128 featmlp producers first (resident
    // first -> no deadlock), then 2048 consumer blocks x 4 groupnet waves.
    fused_kernel<<<NPROD + (BB * MM) / 4, 256, 0, stream>>>(
        pts, centf, out, feat, fw1, fb1, fw2, fb2, fw3, fb3, fout,
        pw1, pb1, pw2, pb2, pw3, pb3,
        out + (size_t)BB * MM * 3, flags);
}

// Round 10
// 804.596 us; speedup vs baseline: 1.6847x; 1.0080x over previous
//
#include <hip/hip_runtime.h>
#include <hip/hip_bf16.h>

// Problem constants (B=8, N=4096, M=N/4, K=64, C_in=64, h=128)
#define BB   8
#define NN   4096
#define MM   1024
#define KK   64
#define CIN  64
#define HH   128

// f32 radius^2 predicate: largest f32 <= 0.2*0.2 (f64) = 0x3D23D70A.
#define R2F 0.039999999105930328f

#define NPROD (BB + (BB * NN) / 256)   // 136 producer blocks (8 FPS + 128 featmlp)
#define H2SU  36                        // u32 stride per k-row (32 data + 4 pad)
#define SMEMF 21504                     // 86KB LDS -> 1 block/CU: FPS isolation
#define FLG(b) ((b) * 16)               // flags padded to one 64B line each
#define FDONE  128                      // featmlp done counter index

// Inputs: f32, dict order. Output: f32, values bf16-rounded (matches np ref).
static __device__ __forceinline__ float rnd_bf16(float v) {
    return __bfloat162float(__float2bfloat16(v));
}
// Manual RNE f32->bf16 (finite inputs only; matches RNE for our h2 values).
static __device__ __forceinline__ unsigned int bf16bits(float v) {
    unsigned int u = __float_as_uint(v);
    return (u + 0x7FFFu + ((u >> 16) & 1u)) >> 16;
}
// Wave-local LDS fence: orders this wave's ds writes/reads.
static __device__ __forceinline__ void wavefence() {
    __builtin_amdgcn_wave_barrier();
    __threadfence_block();
    __builtin_amdgcn_wave_barrier();
}

// ---------------------------------------------------------------------------
// ONE fused kernel. Blocks 0..7: FPS. 8..135: featmlp. 136..2183: 4 groupnet
// waves each, spin-waiting on FPS progress (R19 overlap, PROVEN -123us).
//
// R25 = R24 resubmitted verbatim (R24 bench: container failed twice =
// infra; kernel audited deadlock-free -- uniform branches, both barriers
// reached by all threads, final publish MM=1024 covers max wait 1023,
// producers never wait). POLL-TRAFFIC REDUCTION: R23 proved store batching
// null (3rd null on the FPS stretch). Remaining channel: ~992 spinning
// waves x agent-scope atomic load every ~600cy = ~1.6 polls/cy crossing
// the fabric to the coherence point for the whole 740us -> fabric/DVFS
// pressure on the FPS serial chain. Fix: (a) ONE poller wave per consumer
// block (all 4 waves' m are in the same 16-publish cohort -> wave 0 waits
// for flags[b] > m_base+3, then __syncthreads; waves 1-3 do ONE acquire
// load each post-barrier to keep their own L1/L2 invalidate before reading
// centf). (b) same for the fdone wait. (c) sleeps lengthened to 32/127.
// ~16x less sustained poll traffic. FPS/featmlp/consumer arithmetic
// byte-identical to passing R23.
//
// FPS ledger: R11 atomic=631 floor(solo). R12 512thr=790. R13 slot-split=694.
// R15 ds_permute=1068. R16 pk+tree=772. R18 DPP=862. R20 setprio=null.
// R22 1blk/CU=-40. R23 store-batch=null. DO NOT attack atomic/reduce/stores.
// Groupnet ledger: R17 1-wave-per-group GOOD; R18 4-wave-split REGRESSED.
// ---------------------------------------------------------------------------
__global__ __launch_bounds__(256) void fused_kernel(
    const float* __restrict__ pts,            // [B,3,N] f32
    float* __restrict__ centf,                // ws [B,M,3] f32 (exact)
    float* __restrict__ outc,                 // d_out (first B*M*3), f32
    const float* __restrict__ feat,           // [B,CIN,N] f32
    const float* __restrict__ fw1, const float* __restrict__ fb1,
    const float* __restrict__ fw2, const float* __restrict__ fb2,
    const float* __restrict__ fw3, const float* __restrict__ fb3,
    __hip_bfloat16* __restrict__ fout,        // ws [B,N,HH] bf16
    const float* __restrict__ pw1, const float* __restrict__ pb1,
    const float* __restrict__ pw2, const float* __restrict__ pb2,
    const float* __restrict__ pw3, const float* __restrict__ pb3,
    float* __restrict__ outf,                 // d_out + B*M*3: [B,256,M] f32
    unsigned int* __restrict__ flags)         // ws: padded progress + fdone
{
    __shared__ float smem[SMEMF];             // 86KB: pad forces 1 block/CU
    __shared__ unsigned long long akey[4];
    __shared__ float lsbuf[48];               // FPS: 16-centroid store ring
    const int t = threadIdx.x;

    if (blockIdx.x < BB) {
        // ================= FPS (R11 body + batched stores) =================
        const int b = blockIdx.x;
        float* lx = smem;
        float* ly = smem + NN;
        float* lz = smem + 2 * NN;

        const float* px = pts + (size_t)b * 3 * NN;
        float x[16], y[16], z[16], mind[16];
#pragma unroll
        for (int i = 0; i < 16; ++i) {
            int p = t + i * 256;              // coalesced
            x[i] = px[p];
            y[i] = px[NN + p];
            z[i] = px[2 * NN + p];
            lx[p] = x[i]; ly[p] = y[i]; lz[p] = z[i];
            mind[i] = 3.4e38f;
        }
        if (t < 4) akey[t] = 0ULL;
        __syncthreads();

        float bx = lx[0], by = ly[0], bz = lz[0];

        for (int j = 0; j < MM; ++j) {
            if (t == 0) {
                lsbuf[(j & 15) * 3 + 0] = bx; // LDS ring: no global store here
                lsbuf[(j & 15) * 3 + 1] = by;
                lsbuf[(j & 15) * 3 + 2] = bz;
                if ((j & 15) == 1 && j > 16)  // flush j-17..j-2 drained by now
                    __hip_atomic_store(&flags[FLG(b)], (unsigned int)(j - 1),
                                       __ATOMIC_RELEASE, __HIP_MEMORY_SCOPE_AGENT);
                akey[(j + 2) & 3] = 0ULL;     // reset future slot (race-free)
            }
            float bd = -1.0f; int bi = 0;
#pragma unroll
            for (int i = 0; i < 16; ++i) {
                float dx = x[i] - bx, dy = y[i] - by, dz = z[i] - bz;
                // exact np order: (dx*dx + dy*dy) + dz*dz, RN, no fma
                float d = __fadd_rn(__fadd_rn(__fmul_rn(dx, dx), __fmul_rn(dy, dy)),
                                    __fmul_rn(dz, dz));
                float md = fminf(mind[i], d);
                mind[i] = md;
                if (md > bd) { bd = md; bi = t + i * 256; }  // strict >: smaller idx
            }
            unsigned long long key =
                ((unsigned long long)__float_as_uint(bd) << 32) |
                (unsigned long long)(0xFFFFFFFFu - (unsigned)bi);
            atomicMax(&akey[j & 3], key);
            __syncthreads();
            if ((j & 15) == 15) {             // flush centroids j-15..j
                const int base = (b * MM + (j - 15)) * 3;
                if (t < 48)       centf[base + t]      = lsbuf[t];
                else if (t < 96)  outc[base + (t - 48)] = rnd_bf16(lsbuf[t - 48]);
            }
            unsigned long long bk = akey[j & 3];
            int best = (int)(0xFFFFFFFFu - (unsigned)(bk & 0xFFFFFFFFULL));
            bx = lx[best]; by = ly[best]; bz = lz[best];
        }
        __syncthreads();                      // drain final flush stores
        if (t == 0)
            __hip_atomic_store(&flags[FLG(b)], (unsigned int)MM,
                               __ATOMIC_RELEASE, __HIP_MEMORY_SCOPE_AGENT);
    } else if (blockIdx.x < NPROD) {
        // ================= featmlp path (+ done counter) =================
        float* w1 = smem;
        float* w2 = smem + CIN * CIN;
        for (int i = t; i < CIN * CIN; i += 256) { w1[i] = fw1[i]; w2[i] = fw2[i]; }
        __syncthreads();

        const int gid = (blockIdx.x - BB) * 256 + t;   // b*N + n
        const int b = gid >> 12, n = gid & (NN - 1);
        const float* fp = feat + (size_t)b * CIN * NN + n;

        float f[CIN];
#pragma unroll
        for (int c = 0; c < CIN; ++c) f[c] = fp[(size_t)c * NN];

        float h1[CIN];
        for (int o = 0; o < CIN; ++o) {
            float acc = fb1[o];
#pragma unroll
            for (int c = 0; c < CIN; ++c) acc = fmaf(f[c], w1[o * CIN + c], acc);
            h1[o] = fmaxf(acc, 0.f);
        }
        float h2[CIN];
        for (int o = 0; o < CIN; ++o) {
            float acc = fb2[o];
#pragma unroll
            for (int c = 0; c < CIN; ++c) acc = fmaf(h1[c], w2[o * CIN + c], acc);
            h2[o] = fmaxf(acc, 0.f);
        }
        __hip_bfloat16* op = fout + (size_t)gid * HH;
        for (int o = 0; o < HH; ++o) {
            float acc = fb3[o];
#pragma unroll
            for (int c = 0; c < CIN; ++c) acc = fmaf(h2[c], fw3[o * CIN + c], acc);
            op[o] = __float2bfloat16(acc);
        }
        __threadfence();                      // my fout stores -> agent visible
        __syncthreads();
        if (t == 0)
            __hip_atomic_fetch_add(&flags[FDONE], 1u,
                                   __ATOMIC_RELEASE, __HIP_MEMORY_SCOPE_AGENT);
    } else {
        // ============ groupnet: 4 independent waves per block ============
        // Batch-interleaved mapping: resident window tracks all 8 batches.
        const int wv = t >> 6, lane = t & 63;
        unsigned int* h2w = ((unsigned int*)smem) + wv * (KK * H2SU);   // 9.2KB/wave
        int* selw = ((int*)smem) + 4 * (KK * H2SU) + wv * KK;           // 256B/wave

        const int idx = blockIdx.x - NPROD;            // 0..2047
        const int b = idx & 7;
        const int m_base = (idx >> 3) * 4;             // 4 m's, one cohort
        const int m = m_base + wv;                     // 0..1023
        const int g = b * MM + m;

        // Single-poller wait: wave 0 spins for the whole block (all 4 m's
        // are in the same 16-publish cohort -> simultaneous readiness).
        if (wv == 0) {
            unsigned int prog;
            while ((prog = __hip_atomic_load(&flags[FLG(b)], __ATOMIC_RELAXED,
                                             __HIP_MEMORY_SCOPE_AGENT))
                   <= (unsigned)(m_base + 3)) {
                if ((unsigned)(m_base + 3) - prog > 128u)
                    __builtin_amdgcn_s_sleep(127);
                else
                    __builtin_amdgcn_s_sleep(32);
            }
            (void)__hip_atomic_load(&flags[FLG(b)], __ATOMIC_ACQUIRE,
                                    __HIP_MEMORY_SCOPE_AGENT);
        }
        __syncthreads();                               // barrier #1
        if (wv != 0)                                   // own acquire: L1/L2
            (void)__hip_atomic_load(&flags[FLG(b)], __ATOMIC_ACQUIRE,
                                    __HIP_MEMORY_SCOPE_AGENT);

        const float* pts_b = pts + (size_t)b * 3 * NN;
        const float cx = centf[(size_t)g * 3];
        const float cy = centf[(size_t)g * 3 + 1];
        const float cz = centf[(size_t)g * 3 + 2];

        // ---- 1) ball query: 4-deep software pipeline (R17) ----
        int cnt = 0, first = 0;
        bool have_first = false;
        float fx[4], fy[4], fz[4];
#pragma unroll
        for (int q = 0; q < 4; ++q) {
            int p = q * 64 + lane;
            fx[q] = pts_b[p]; fy[q] = pts_b[NN + p]; fz[q] = pts_b[2 * NN + p];
        }
        for (int base = 0; base < NN; base += 256) {
#pragma unroll
            for (int q = 0; q < 4; ++q) {      // q static: regs stay in VGPRs
                const int cb = base + q * 64;
                float vx = fx[q], vy = fy[q], vz = fz[q];
                const int pre = cb + 256 + lane;
                if (pre < NN) {
                    fx[q] = pts_b[pre]; fy[q] = pts_b[NN + pre]; fz[q] = pts_b[2 * NN + pre];
                }
                float dx = vx - cx, dy = vy - cy, dz = vz - cz;
                float d2 = __fadd_rn(__fadd_rn(__fmul_rn(dx, dx), __fmul_rn(dy, dy)),
                                     __fmul_rn(dz, dz));
                bool in = (d2 <= R2F);
                unsigned long long mask = __ballot(in);
                if (!have_first && mask != 0ULL) {
                    first = cb + (int)__builtin_ctzll(mask);
                    have_first = true;
                }
                int pos = cnt + (int)__popcll(mask & ((1ULL << lane) - 1ULL));
                if (in && pos < KK) selw[pos] = cb + lane;
                cnt += (int)__popcll(mask);
            }
        }
        if (cnt < KK) {
            for (int q = cnt + lane; q < KK; q += 64) selw[q] = first;
        }
        wavefence();                           // selw visible within wave

        const int s = selw[lane];
        float* ob = outf + (size_t)b * 256 * MM + m;

        // ---- 2) point layers 1-2 (lane = slot k); 8 parallel chains ----
        {
            const float x = pts_b[s]          - cx;
            const float y = pts_b[NN + s]     - cy;
            const float z = pts_b[2 * NN + s] - cz;
            float h1[CIN];
#pragma unroll
            for (int o = 0; o < CIN; ++o) {
                float acc = pb1[o];
                acc = fmaf(x, pw1[o * 3 + 0], acc);
                acc = fmaf(y, pw1[o * 3 + 1], acc);
                acc = fmaf(z, pw1[o * 3 + 2], acc);
                h1[o] = fmaxf(acc, 0.f);
            }
            for (int o8 = 0; o8 < CIN / 8; ++o8) { // 8 outputs per iter
                float a[8];
#pragma unroll
                for (int q = 0; q < 8; ++q) a[q] = pb2[o8 * 8 + q];
                for (int c = 0; c < CIN; ++c) {
                    float hc = h1[c];
#pragma unroll
                    for (int q = 0; q < 8; ++q)
                        a[q] = fmaf(hc, pw2[(o8 * 8 + q) * CIN + c], a[q]);
                }
                uint4 pk;
                pk.x = bf16bits(fmaxf(a[0], 0.f)) | (bf16bits(fmaxf(a[1], 0.f)) << 16);
                pk.y = bf16bits(fmaxf(a[2], 0.f)) | (bf16bits(fmaxf(a[3], 0.f)) << 16);
                pk.z = bf16bits(fmaxf(a[4], 0.f)) | (bf16bits(fmaxf(a[5], 0.f)) << 16);
                pk.w = bf16bits(fmaxf(a[6], 0.f)) | (bf16bits(fmaxf(a[7], 0.f)) << 16);
                *(uint4*)&h2w[lane * H2SU + o8 * 4] = pk;
            }
        }
        wavefence();                           // h2w complete within wave

        // ---- 3) point layer 3 + group max -> out ch 128..255 (R17) ----
        {
            float w3a[CIN], w3b[CIN];
#pragma unroll
            for (int c = 0; c < CIN; ++c) {
                w3a[c] = pw3[(size_t)lane * CIN + c];
                w3b[c] = pw3[(size_t)(lane + 64) * CIN + c];
            }
            const float b3a = pb3[lane], b3b = pb3[lane + 64];
            float pa0 = -3.4e38f, pb0 = -3.4e38f;  // k in [0,32)
            float pa1 = -3.4e38f, pb1v = -3.4e38f; // k in [32,64)
            for (int k = 0; k < KK / 2; ++k) {
                float va0 = b3a, vb0 = b3b, va1 = b3a, vb1 = b3b;
#pragma unroll
                for (int u4 = 0; u4 < 8; ++u4) {   // 8 uint4 = 32 u32 = 64 bf16
                    uint4 p0 = *(const uint4*)&h2w[k * H2SU + u4 * 4];
                    uint4 p1 = *(const uint4*)&h2w[(k + 32) * H2SU + u4 * 4];
                    const unsigned int* w0 = &p0.x;
                    const unsigned int* w1 = &p1.x;
#pragma unroll
                    for (int jj = 0; jj < 4; ++jj) {
                        int c = u4 * 8 + jj * 2;
                        float h0lo = __uint_as_float(w0[jj] << 16);
                        float h0hi = __uint_as_float(w0[jj] & 0xFFFF0000u);
                        float h1lo = __uint_as_float(w1[jj] << 16);
                        float h1hi = __uint_as_float(w1[jj] & 0xFFFF0000u);
                        va0 = fmaf(h0lo, w3a[c],     va0); vb0 = fmaf(h0lo, w3b[c],     vb0);
                        va1 = fmaf(h1lo, w3a[c],     va1); vb1 = fmaf(h1lo, w3b[c],     vb1);
                        va0 = fmaf(h0hi, w3a[c + 1], va0); vb0 = fmaf(h0hi, w3b[c + 1], vb0);
                        va1 = fmaf(h1hi, w3a[c + 1], va1); vb1 = fmaf(h1hi, w3b[c + 1], vb1);
                    }
                }
                pa0 = fmaxf(pa0, va0); pb0  = fmaxf(pb0,  vb0);
                pa1 = fmaxf(pa1, va1); pb1v = fmaxf(pb1v, vb1);
            }
            ob[(size_t)(128 + lane) * MM] = rnd_bf16(fmaxf(pa0, pa1));
            ob[(size_t)(192 + lane) * MM] = rnd_bf16(fmaxf(pb0, pb1v));
        }

        // ---- 4) feature gather-max; single-poller wait for featmlp ----
        if (wv == 0) {
            while (__hip_atomic_load(&flags[FDONE], __ATOMIC_RELAXED,
                                     __HIP_MEMORY_SCOPE_AGENT)
                   < (unsigned)(NPROD - BB))
                __builtin_amdgcn_s_sleep(32);
            (void)__hip_atomic_load(&flags[FDONE], __ATOMIC_ACQUIRE,
                                    __HIP_MEMORY_SCOPE_AGENT);
        }
        __syncthreads();                               // barrier #2
        if (wv != 0)                                   // own acquire: L1/L2
            (void)__hip_atomic_load(&flags[FDONE], __ATOMIC_ACQUIRE,
                                    __HIP_MEMORY_SCOPE_AGENT);
        {
            const __hip_bfloat16* fb_ = fout + (size_t)b * NN * HH;
            unsigned int pf[4];
#pragma unroll
            for (int q = 0; q < 4; ++q)
                pf[q] = ((const unsigned int*)(fb_ + (size_t)selw[q] * HH))[lane];
            float alo[4], ahi[4];
#pragma unroll
            for (int q = 0; q < 4; ++q) { alo[q] = -3.4e38f; ahi[q] = -3.4e38f; }
            for (int k = 0; k < KK; k += 4) {
#pragma unroll
                for (int q = 0; q < 4; ++q) {  // q static: pf stays in VGPRs
                    unsigned int wversion = pf[q];
                    int nk = k + 4 + q;
                    if (nk < KK)
                        pf[q] = ((const unsigned int*)(fb_ + (size_t)selw[nk] * HH))[lane];
                    alo[q] = fmaxf(alo[q], __uint_as_float(wversion << 16));
                    ahi[q] = fmaxf(ahi[q], __uint_as_float(wversion & 0xFFFF0000u));
                }
            }
            float lo = fmaxf(fmaxf(alo[0], alo[1]), fmaxf(alo[2], alo[3]));
            float hi = fmaxf(fmaxf(ahi[0], ahi[1]), fmaxf(ahi[2], ahi[3]));
            ob[(size_t)(2 * lane) * MM]     = lo;  // values already bf16-exact
            ob[(size_t)(2 * lane + 1) * MM] = hi;
        }
    }
}

extern "C" void kernel_launch(void* const* d_in, const int* in_sizes, int n_in,
                              void* d_out, int out_size, void* d_ws, size_t ws_size,
                              hipStream_t stream) {
    const float* pts  = (const float*)d_in[0];
    const float* feat = (const float*)d_in[1];
    const float* pw1  = (const float*)d_in[2];
    const float* pb1  = (const float*)d_in[3];
    const float* pw2  = (const float*)d_in[4];
    const float* pb2  = (const float*)d_in[5];
    const float* pw3  = (const float*)d_in[6];
    const float* pb3  = (const float*)d_in[7];
    const float* fw1  = (const float*)d_in[8];
    const float* fb1  = (const float*)d_in[9];
    const float* fw2  = (const float*)d_in[10];
    const float* fb2  = (const float*)d_in[11];
    const float* fw3  = (const float*)d_in[12];
    const float* fb3  = (const float*)d_in[13];

    float* out = (float*)d_out;                // f32 output

    // ws: [0,96KB) f32 centroids; [96KB,+8.39MB) bf16 feature-MLP cache;
    // then 1KB padded flags (8 progress lines + fdone).
    float* centf = (float*)d_ws;
    __hip_bfloat16* fout = (__hip_bfloat16*)((char*)d_ws + (size_t)BB * MM * 3 * 4);
    unsigned int* flags = (unsigned int*)((char*)d_ws + (size_t)BB * MM * 3 * 4
                                          + (size_t)BB * NN * HH * 2);

    // flags must be zero at kernel start on EVERY launch/replay.
    hipMemsetAsync(flags, 0, 1024, stream);

    // One fused launch: 8 FPS + 128 featmlp producers first (resident
    // first -> no deadlock), then 2048 consumer blocks x 4 groupnet waves.
    fused_kernel<<<NPROD + (BB * MM) / 4, 256, 0, stream>>>(
        pts, centf, out, feat, fw1, fb1, fw2, fb2, fw3, fb3, fout,
        pw1, pb1, pw2, pb2, pw3, pb3,
        out + (size_t)BB * MM * 3, flags);
}